// Round 1
// baseline (961.022 us; speedup 1.0000x reference)
//
#include <hip/hip_runtime.h>
#include <math.h>

#define DEV __device__ __forceinline__

DEV float sigm(float x){ return 1.f/(1.f+__expf(-x)); }
DEV float siluf(float x){ return x * sigm(x); }
DEV float softplusf(float x){ return x > 20.f ? x : log1pf(__expf(x)); }

static constexpr float NG = 131072.0f;   // group-norm element count per (b,g): 32*64*64

// ---- workspace layout (offsets in floats) ----
static constexpr size_t WS_H1    = 0;          // B*HW*128
static constexpr size_t WS_H1PRE = 1048576;    // B*HW*128 (reused as yproj)
static constexpr size_t WS_XC    = 2097152;    // B*HW*256
static constexpr size_t WS_ZSIL  = 4194304;    // B*HW*256
static constexpr size_t WS_XZ    = 6291456;    // B*HW*512  (xz; later delta/Bm/Cm/logits)
static constexpr size_t WS_DELTA = 6291456;    // B*HW*256
static constexpr size_t WS_BM    = 8388608;    // B*HW*16
static constexpr size_t WS_CM    = 8519680;    // B*HW*16
static constexpr size_t WS_LOG   = 8650752;    // B*HW*16 (logits, stride 16, 10 used)
static constexpr size_t WS_Y     = 10485760;   // B*HW*256 (y; later e_pre B*HW*128)
static constexpr size_t WS_P     = 12582912;   // B*64*256*16
static constexpr size_t WS_Q     = 13107200;
static constexpr size_t WS_HS    = 13631488;
static constexpr size_t WS_Y2    = 14155776;   // B*HW*128
static constexpr size_t WS_FEAT  = 15204352;   // B*HW*128
static constexpr size_t WS_STATS = 16252928;   // 64 floats: pe@0 spa@16 spe@32 ref@48
static constexpr size_t WS_PEWT  = 16253056;   // 128*128
static constexpr size_t WS_INWT  = WS_PEWT  + 16384;  // 128*512
static constexpr size_t WS_OUTWT = WS_INWT  + 65536;  // 256*128
static constexpr size_t WS_XPWT  = WS_OUTWT + 32768;  // 256*40
static constexpr size_t WS_SPEIN = WS_XPWT  + 10240;  // 32*128
static constexpr size_t WS_SPEXP = WS_SPEIN + 4096;   // 64*34
static constexpr size_t WS_SPEOUT= WS_SPEXP + 2176;   // 64*32

// ---------------- transpose weights ----------------
__global__ void __launch_bounds__(256)
k_transpose(const float* __restrict__ pe_w, const float* __restrict__ in_w,
            const float* __restrict__ out_w, const float* __restrict__ xp_w,
            const float* __restrict__ spe_in, const float* __restrict__ spe_xp,
            const float* __restrict__ spe_out,
            float* __restrict__ peT, float* __restrict__ inT,
            float* __restrict__ outT, float* __restrict__ xpT,
            float* __restrict__ speInT, float* __restrict__ speXpT,
            float* __restrict__ speOutT){
  int i0 = blockIdx.x*256 + threadIdx.x;
  int nt = gridDim.x*256;
  for (int k = i0; k < 128*128; k += nt){ int r = k >> 7, c = k & 127; peT[c*128 + r] = pe_w[k]; }
  for (int k = i0; k < 512*128; k += nt){ int r = k >> 7, c = k & 127; inT[c*512 + r] = in_w[k]; }
  for (int k = i0; k < 128*256; k += nt){ int r = k >> 8, c = k & 255; outT[c*128 + r] = out_w[k]; }
  for (int k = i0; k < 40*256;  k += nt){ int r = k >> 8, c = k & 255; xpT[c*40 + r] = xp_w[k]; }
  for (int k = i0; k < 128*32;  k += nt){ int r = k >> 5, c = k & 31;  speInT[c*128 + r] = spe_in[k]; }
  for (int k = i0; k < 34*64;   k += nt){ int r = k >> 6, c = k & 63;  speXpT[c*34 + r] = spe_xp[k]; }
  for (int k = i0; k < 32*64;   k += nt){ int r = k >> 6, c = k & 63;  speOutT[c*32 + r] = spe_out[k]; }
}

// ---------------- pe 1x1 conv + GN stats ----------------
__global__ void __launch_bounds__(256)
k_pe(const float* __restrict__ x, const float* __restrict__ peT,
     const float* __restrict__ pe_b, float* __restrict__ h1pre,
     float* __restrict__ stats){
  __shared__ float xs[128][33];
  __shared__ float red1[4][64], red2[4][64];
  int tid = threadIdx.x;
  int m0 = blockIdx.x * 32;          // global pixel base (B*HW)
  int b = m0 >> 12, pl = m0 & 4095;
  for (int i = tid; i < 32*128; i += 256){
    int t = i >> 7, c = i & 127;
    xs[c][t] = x[(size_t)(b*128 + c)*4096 + pl + t];
  }
  __syncthreads();
  int o = tid & 127, half = tid >> 7;
  float acc[16];
  #pragma unroll
  for (int t = 0; t < 16; t++) acc[t] = 0.f;
  for (int c = 0; c < 128; c++){
    float wv = peT[c*128 + o];
    const float* xr = &xs[c][half*16];
    #pragma unroll
    for (int t = 0; t < 16; t++) acc[t] += wv * xr[t];
  }
  float bo = pe_b[o];
  float s1 = 0.f, s2 = 0.f;
  for (int t = 0; t < 16; t++){
    float vv = acc[t] + bo;
    s1 += vv; s2 += vv*vv;
    h1pre[(size_t)(m0 + half*16 + t)*128 + o] = vv;
  }
  int g = o >> 5, idx = (o & 31) | (half << 5);
  red1[g][idx] = s1; red2[g][idx] = s2;
  __syncthreads();
  int rg = tid >> 6, ridx = tid & 63;
  for (int s = 32; s >= 1; s >>= 1){
    if (ridx < s){ red1[rg][ridx] += red1[rg][ridx+s]; red2[rg][ridx] += red2[rg][ridx+s]; }
    __syncthreads();
  }
  if (ridx == 0){
    atomicAdd(&stats[(b*4+rg)*2+0], red1[rg][0]);
    atomicAdd(&stats[(b*4+rg)*2+1], red2[rg][0]);
  }
}

// ---------------- GN + silu elementwise (pe) ----------------
__global__ void __launch_bounds__(256)
k_gnsilu(const float* __restrict__ pre, const float* __restrict__ stats,
         const float* __restrict__ gw, const float* __restrict__ gb,
         float* __restrict__ outb){
  int idx = blockIdx.x*256 + threadIdx.x;
  int c = idx & 127; int pix = idx >> 7; int b = pix >> 12; int g = c >> 5;
  float s1 = stats[(b*4+g)*2], s2 = stats[(b*4+g)*2+1];
  float m = s1 * (1.f/NG);
  float v = s2 * (1.f/NG) - m*m;
  float xn = (pre[idx] - m) * rsqrtf(v + 1e-5f);
  float val = xn * gw[c] + gb[c];
  outb[idx] = siluf(val);
}

// ---------------- spa in-proj: xz = h1 @ in_w.T ----------------
__global__ void __launch_bounds__(256)
k_xz(const float* __restrict__ h1, const float* __restrict__ inT,
     float* __restrict__ xz){
  __shared__ float xs[128][33];
  int tid = threadIdx.x;
  int m0 = blockIdx.x * 32;
  for (int i = tid; i < 32*128; i += 256){
    int t = i >> 7, c = i & 127;
    xs[c][t] = h1[(size_t)(m0 + t)*128 + c];
  }
  __syncthreads();
  float acc0[32], acc1[32];
  #pragma unroll
  for (int t = 0; t < 32; t++){ acc0[t]=0.f; acc1[t]=0.f; }
  int o = tid;
  for (int c = 0; c < 128; c++){
    float w0 = inT[c*512 + o];
    float w1 = inT[c*512 + o + 256];
    #pragma unroll
    for (int t = 0; t < 32; t++){
      float a = xs[c][t];
      acc0[t] += w0*a; acc1[t] += w1*a;
    }
  }
  for (int t = 0; t < 32; t++){
    xz[(size_t)(m0+t)*512 + o]       = acc0[t];
    xz[(size_t)(m0+t)*512 + o + 256] = acc1[t];
  }
}

// ---------------- causal depthwise conv K=4 + silu; z->silu(z) ----------------
__global__ void __launch_bounds__(256)
k_conv(const float* __restrict__ xz, const float* __restrict__ cw,
       const float* __restrict__ cb, float* __restrict__ xc,
       float* __restrict__ zsil){
  int idx = blockIdx.x*256 + threadIdx.x;   // B*4096*256
  int d = idx & 255;
  int l = (idx >> 8) & 4095;
  int b = idx >> 20;
  float v = cb[d];
  #pragma unroll
  for (int k = 0; k < 4; k++){
    int ls = l - 3 + k;
    if (ls >= 0) v += xz[(size_t)(b*4096 + ls)*512 + d] * cw[d*4 + k];
  }
  xc[idx] = siluf(v);
  float z = xz[(size_t)(b*4096 + l)*512 + 256 + d];
  zsil[idx] = siluf(z);
}

// ---------------- x-proj (dt,B,C) + delta=softplus(dt@dtw.T+dtb) ----------------
__global__ void __launch_bounds__(256)
k_proj(const float* __restrict__ xc, const float* __restrict__ xpT,
       const float* __restrict__ dtw, const float* __restrict__ dtb,
       float* __restrict__ delta, float* __restrict__ Bm, float* __restrict__ Cm){
  __shared__ float xt[32][260];
  __shared__ float pr[32][40];
  int tid = threadIdx.x;
  int m0 = blockIdx.x * 32;
  for (int i = tid; i < 32*256; i += 256){
    int t = i >> 8, d = i & 255;
    xt[t][d] = xc[(size_t)(m0+t)*256 + d];
  }
  __syncthreads();
  {
    int t = tid >> 3, j0 = tid & 7;
    float a0=0.f,a1=0.f,a2=0.f,a3=0.f,a4=0.f;
    for (int d = 0; d < 256; d++){
      float xv = xt[t][d];
      const float* wp = &xpT[d*40 + j0];
      a0 += xv*wp[0]; a1 += xv*wp[8]; a2 += xv*wp[16]; a3 += xv*wp[24]; a4 += xv*wp[32];
    }
    pr[t][j0] = a0; pr[t][j0+8] = a1; pr[t][j0+16] = a2; pr[t][j0+24] = a3; pr[t][j0+32] = a4;
  }
  __syncthreads();
  {
    int d = tid;
    float w[8];
    #pragma unroll
    for (int r = 0; r < 8; r++) w[r] = dtw[d*8+r];
    float bd = dtb[d];
    for (int t = 0; t < 32; t++){
      float val = bd;
      #pragma unroll
      for (int r = 0; r < 8; r++) val += pr[t][r]*w[r];
      delta[(size_t)(m0+t)*256 + d] = softplusf(val);
    }
  }
  for (int i = tid; i < 512; i += 256){
    int t = i >> 4, n = i & 15;
    Bm[(size_t)(m0+t)*16 + n] = pr[t][8+n];
    Cm[(size_t)(m0+t)*16 + n] = pr[t][24+n];
  }
}

// ---------------- chunked scan phase 1: per-chunk (P,Q) ----------------
__global__ void __launch_bounds__(256)
k_scan1(const float* __restrict__ delta, const float* __restrict__ xc,
        const float* __restrict__ Bm, const float* __restrict__ Alog,
        float* __restrict__ P, float* __restrict__ Q){
  __shared__ float sd[64][16], sx[64][16], sb[64][16];
  int blk = blockIdx.x;            // 2*64*16
  int b = blk >> 10;
  int chunk = (blk >> 4) & 63;
  int dblk = blk & 15;
  int tid = threadIdx.x;
  size_t rowbase = (size_t)(b*4096 + chunk*64);
  for (int i = tid; i < 64*16; i += 256){
    int ii = i >> 4, dd = i & 15;
    sd[ii][dd] = delta[(rowbase + ii)*256 + dblk*16 + dd];
    sx[ii][dd] = xc  [(rowbase + ii)*256 + dblk*16 + dd];
    sb[ii][dd] = Bm  [(rowbase + ii)*16 + dd];
  }
  int dl = tid >> 4, n = tid & 15;
  int d = dblk*16 + dl;
  float An = -__expf(Alog[d*16 + n]);
  __syncthreads();
  float Pv = 1.f, Qv = 0.f;
  for (int i = 0; i < 64; i++){
    float dv = sd[i][dl];
    float a = __expf(dv * An);
    Qv = a*Qv + dv * sb[i][n] * sx[i][dl];
    Pv *= a;
  }
  size_t o = (size_t)(b*64+chunk)*4096 + dblk*256 + tid;
  P[o] = Pv; Q[o] = Qv;
}

// ---------------- chunked scan phase 2: cross-chunk sequential ----------------
__global__ void __launch_bounds__(256)
k_scan2(const float* __restrict__ P, const float* __restrict__ Q,
        float* __restrict__ hs){
  int gid = blockIdx.x*256 + threadIdx.x;  // 8192 = B*256*16
  int b = gid >> 12, dn = gid & 4095;
  float h = 0.f;
  for (int ch = 0; ch < 64; ch++){
    size_t idx = (size_t)(b*64 + ch)*4096 + dn;
    hs[idx] = h;
    h = P[idx]*h + Q[idx];
  }
}

// ---------------- chunked scan phase 3: replay + y ----------------
__global__ void __launch_bounds__(256)
k_scan3(const float* __restrict__ delta, const float* __restrict__ xc,
        const float* __restrict__ Bm, const float* __restrict__ Cm,
        const float* __restrict__ zsil, const float* __restrict__ Alog,
        const float* __restrict__ Dv, const float* __restrict__ hs,
        float* __restrict__ y){
  __shared__ float sd[64][16], sx[64][16], sb[64][16], sc[64][16], sz[64][16], yt[64][16];
  int blk = blockIdx.x;
  int b = blk >> 10;
  int chunk = (blk >> 4) & 63;
  int dblk = blk & 15;
  int tid = threadIdx.x;
  size_t rowbase = (size_t)(b*4096 + chunk*64);
  for (int i = tid; i < 64*16; i += 256){
    int ii = i >> 4, dd = i & 15;
    sd[ii][dd] = delta[(rowbase + ii)*256 + dblk*16 + dd];
    sx[ii][dd] = xc  [(rowbase + ii)*256 + dblk*16 + dd];
    sz[ii][dd] = zsil[(rowbase + ii)*256 + dblk*16 + dd];
    sb[ii][dd] = Bm  [(rowbase + ii)*16 + dd];
    sc[ii][dd] = Cm  [(rowbase + ii)*16 + dd];
  }
  int dl = tid >> 4, n = tid & 15;
  int d = dblk*16 + dl;
  float An = -__expf(Alog[d*16 + n]);
  float h = hs[(size_t)(b*64+chunk)*4096 + dblk*256 + tid];
  float Dd = Dv[d];
  __syncthreads();
  for (int i = 0; i < 64; i++){
    float dv = sd[i][dl], xv = sx[i][dl];
    float a = __expf(dv * An);
    h = a*h + dv * sb[i][n] * xv;
    float ctr = h * sc[i][n];
    ctr += __shfl_xor(ctr, 1);
    ctr += __shfl_xor(ctr, 2);
    ctr += __shfl_xor(ctr, 4);
    ctr += __shfl_xor(ctr, 8);
    if (n == 0) yt[i][dl] = (ctr + Dd*xv) * sz[i][dl];
  }
  __syncthreads();
  for (int i = tid; i < 1024; i += 256){
    int ii = i >> 4, dd = i & 15;
    y[(rowbase + ii)*256 + dblk*16 + dd] = yt[ii][dd];
  }
}

// ---------------- spa out-proj + GN stats ----------------
__global__ void __launch_bounds__(256)
k_outproj(const float* __restrict__ y, const float* __restrict__ outT,
          float* __restrict__ yproj, float* __restrict__ stats){
  __shared__ float ytile[256][33];
  __shared__ float red1[4][64], red2[4][64];
  int tid = threadIdx.x;
  int m0 = blockIdx.x * 32;
  int b = m0 >> 12;
  for (int i = tid; i < 32*256; i += 256){
    int t = i >> 8, d = i & 255;
    ytile[d][t] = y[(size_t)(m0+t)*256 + d];
  }
  __syncthreads();
  int o = tid & 127, half = tid >> 7;
  float acc[16];
  #pragma unroll
  for (int t = 0; t < 16; t++) acc[t] = 0.f;
  for (int d = 0; d < 256; d++){
    float wv = outT[d*128 + o];
    const float* yr = &ytile[d][half*16];
    #pragma unroll
    for (int t = 0; t < 16; t++) acc[t] += wv * yr[t];
  }
  float s1 = 0.f, s2 = 0.f;
  for (int t = 0; t < 16; t++){
    float vv = acc[t];
    s1 += vv; s2 += vv*vv;
    yproj[(size_t)(m0 + half*16 + t)*128 + o] = vv;
  }
  int g = o >> 5, idx = (o & 31) | (half << 5);
  red1[g][idx] = s1; red2[g][idx] = s2;
  __syncthreads();
  int rg = tid >> 6, ridx = tid & 63;
  for (int s = 32; s >= 1; s >>= 1){
    if (ridx < s){ red1[rg][ridx] += red1[rg][ridx+s]; red2[rg][ridx] += red2[rg][ridx+s]; }
    __syncthreads();
  }
  if (ridx == 0){
    atomicAdd(&stats[16 + (b*4+rg)*2+0], red1[rg][0]);
    atomicAdd(&stats[16 + (b*4+rg)*2+1], red2[rg][0]);
  }
}

// ---------------- spectral mamba: one wave per pixel ----------------
__global__ void __launch_bounds__(256)
k_spe(const float* __restrict__ h1, const float* __restrict__ speInT,
      const float* __restrict__ speXpT, const float* __restrict__ speOutT,
      const float* __restrict__ conv_w, const float* __restrict__ conv_b,
      const float* __restrict__ dt_w, const float* __restrict__ dt_b,
      const float* __restrict__ Alog, const float* __restrict__ Dvec,
      float* __restrict__ y2, float* __restrict__ stats){
  __shared__ float w_inT[32][128];
  __shared__ float w_xpT[64][34];
  __shared__ float w_outT[64][32];
  __shared__ float w_dtw[64][2];
  __shared__ float w_cw[64][4];
  __shared__ float w_cb[64], w_db[64], w_D[64];
  __shared__ float w_At[16][64];   // [n][d] = -exp(Alog[d][n])
  __shared__ float s_in[4][128];
  __shared__ float s_xc[4][4][64];
  __shared__ float s_pr[4][4][34];
  __shared__ float s_y[4][4][64];
  __shared__ float bst[8];
  int tid = threadIdx.x;
  for (int i = tid; i < 4096; i += 256) ((float*)w_inT)[i] = speInT[i];
  for (int i = tid; i < 64*34; i += 256) ((float*)w_xpT)[i] = speXpT[i];
  for (int i = tid; i < 2048; i += 256) ((float*)w_outT)[i] = speOutT[i];
  if (tid < 128) ((float*)w_dtw)[tid] = dt_w[tid];
  ((float*)w_cw)[tid] = conv_w[tid];
  if (tid < 64){ w_cb[tid] = conv_b[tid]; w_db[tid] = dt_b[tid]; w_D[tid] = Dvec[tid]; }
  for (int i = tid; i < 1024; i += 256){
    int d = i & 63, n = i >> 6;
    w_At[n][d] = -__expf(Alog[d*16 + n]);
  }
  if (tid < 8) bst[tid] = 0.f;
  __syncthreads();
  int w = tid >> 6, lane = tid & 63;
  int pix = blockIdx.x*4 + w;
  // phase 0: load pixel channels
  {
    const float2* h2 = (const float2*)(h1 + (size_t)pix*128);
    float2 v = h2[lane];
    s_in[w][2*lane] = v.x; s_in[w][2*lane+1] = v.y;
  }
  // phase 1: in-proj (x part in regs for own d=lane, z part too)
  float xpr[4], zr[4], xcr[4], dlr[4];
  #pragma unroll
  for (int l = 0; l < 4; l++){
    float acc0 = 0.f, acc1 = 0.f;
    #pragma unroll
    for (int c = 0; c < 32; c++){
      float sv = s_in[w][l*32+c];
      acc0 += sv * w_inT[c][lane];
      acc1 += sv * w_inT[c][64+lane];
    }
    xpr[l] = acc0; zr[l] = acc1;
  }
  // phase 2: causal conv K=4 + silu (depthwise over l, own lane only)
  {
    int d = lane;
    float cb = w_cb[d];
    #pragma unroll
    for (int l = 0; l < 4; l++){
      float v = cb;
      #pragma unroll
      for (int k = 0; k < 4; k++){
        int ls = l - 3 + k;
        if (ls >= 0) v += xpr[ls] * w_cw[d][k];
      }
      float sx = siluf(v);
      s_xc[w][l][d] = sx;
      xcr[l] = sx;
    }
  }
  // phase 3: x-proj (34 outputs, lanes<34)
  if (lane < 34){
    #pragma unroll
    for (int l = 0; l < 4; l++){
      float acc = 0.f;
      for (int dd = 0; dd < 64; dd++) acc += s_xc[w][l][dd] * w_xpT[dd][lane];
      s_pr[w][l][lane] = acc;
    }
  }
  // phase 3b: delta
  {
    int d = lane;
    float w0 = w_dtw[d][0], w1 = w_dtw[d][1], bdd = w_db[d];
    #pragma unroll
    for (int l = 0; l < 4; l++)
      dlr[l] = softplusf(bdd + s_pr[w][l][0]*w0 + s_pr[w][l][1]*w1);
  }
  // phase 4: scan (L=4, n in registers)
  {
    int d = lane;
    float h[16];
    #pragma unroll
    for (int n = 0; n < 16; n++) h[n] = 0.f;
    float Dd = w_D[d];
    #pragma unroll
    for (int l = 0; l < 4; l++){
      float dv = dlr[l], xv = xcr[l];
      float ys = 0.f;
      #pragma unroll
      for (int n = 0; n < 16; n++){
        float a = __expf(dv * w_At[n][d]);
        h[n] = a*h[n] + dv * s_pr[w][l][2+n] * xv;
        ys += h[n] * s_pr[w][l][18+n];
      }
      s_y[w][l][d] = (ys + Dd*xv) * siluf(zr[l]);
    }
  }
  // phase 5: out-proj + GN stats (group of channel l*32+c2 is l)
  #pragma unroll
  for (int pass = 0; pass < 2; pass++){
    int l = (lane >> 5) + pass*2;
    int c2 = lane & 31;
    float acc = 0.f;
    for (int dd = 0; dd < 64; dd++) acc += s_y[w][l][dd] * w_outT[dd][c2];
    y2[(size_t)pix*128 + l*32 + c2] = acc;
    float a1 = acc, a2 = acc*acc;
    a1 += __shfl_xor(a1,1);  a2 += __shfl_xor(a2,1);
    a1 += __shfl_xor(a1,2);  a2 += __shfl_xor(a2,2);
    a1 += __shfl_xor(a1,4);  a2 += __shfl_xor(a2,4);
    a1 += __shfl_xor(a1,8);  a2 += __shfl_xor(a2,8);
    a1 += __shfl_xor(a1,16); a2 += __shfl_xor(a2,16);
    if ((lane & 31) == 0){
      atomicAdd(&bst[l*2+0], a1);
      atomicAdd(&bst[l*2+1], a2);
    }
  }
  __syncthreads();
  if (tid < 8){
    int b = (blockIdx.x*4) >> 12;
    atomicAdd(&stats[32 + b*8 + tid], bst[tid]);
  }
}

// ---------------- fuse: GN(spa)+GN(spe)+h1 -> feat, logits ----------------
__global__ void __launch_bounds__(256)
k_fuse(const float* __restrict__ h1, const float* __restrict__ yproj,
       const float* __restrict__ y2, const float* __restrict__ stats,
       const float* __restrict__ spa_g, const float* __restrict__ spa_b,
       const float* __restrict__ spe_g, const float* __restrict__ spe_b,
       const float* __restrict__ fuse_w, const float* __restrict__ cls_w,
       const float* __restrict__ cls_b, float* __restrict__ feat,
       float* __restrict__ logits){
  __shared__ float ft[2][128];
  int tid = threadIdx.x;
  int pixl = tid >> 7, c = tid & 127;
  int pix = blockIdx.x*2 + pixl;
  int b = pix >> 12, g = c >> 5;
  float m1 = stats[16 + (b*4+g)*2]   * (1.f/NG);
  float v1 = stats[16 + (b*4+g)*2+1] * (1.f/NG) - m1*m1;
  float m2 = stats[32 + (b*4+g)*2]   * (1.f/NG);
  float v2 = stats[32 + (b*4+g)*2+1] * (1.f/NG) - m2*m2;
  float h = h1[(size_t)pix*128 + c];
  float sa = siluf((yproj[(size_t)pix*128+c] - m1)*rsqrtf(v1+1e-5f)*spa_g[c] + spa_b[c]) + h;
  float sp = h + siluf((y2[(size_t)pix*128+c] - m2)*rsqrtf(v2+1e-5f)*spe_g[c] + spe_b[c]);
  float e0 = __expf(fuse_w[0]), e1 = __expf(fuse_w[1]);
  float w0 = e0/(e0+e1), w1 = e1/(e0+e1);
  float f = sa*w0 + sp*w1 + h;
  feat[(size_t)pix*128+c] = f;
  ft[pixl][c] = f;
  __syncthreads();
  if (tid < 20){
    int pl = (tid >= 10) ? 1 : 0;
    int o = tid - pl*10;
    float acc = cls_b[o];
    for (int cc = 0; cc < 128; cc++) acc += ft[pl][cc]*cls_w[o*128+cc];
    logits[(size_t)(blockIdx.x*2 + pl)*16 + o] = acc;
  }
}

// ---------------- depthwise 3x3 on feat + GN stats ----------------
__global__ void __launch_bounds__(256)
k_dw(const float* __restrict__ feat, const float* __restrict__ dww,
     float* __restrict__ epre, float* __restrict__ stats){
  __shared__ float red1[4][64], red2[4][64];
  int tid = threadIdx.x;
  int pixl = tid >> 7, c = tid & 127;
  int pix = blockIdx.x*2 + pixl;
  int b = pix >> 12, p = pix & 4095, yy = p >> 6, xx = p & 63;
  float acc = 0.f;
  for (int dy = -1; dy <= 1; dy++){
    int ny = yy + dy; if (ny < 0 || ny > 63) continue;
    for (int dx = -1; dx <= 1; dx++){
      int nx = xx + dx; if (nx < 0 || nx > 63) continue;
      acc += feat[(size_t)((b<<12)|(ny<<6)|nx)*128 + c] * dww[c*9 + (dy+1)*3 + (dx+1)];
    }
  }
  epre[(size_t)pix*128 + c] = acc;
  int g = c >> 5;
  int idx = (c & 31) | (pixl << 5);
  red1[g][idx] = acc; red2[g][idx] = acc*acc;
  __syncthreads();
  int rg = tid >> 6, ridx = tid & 63;
  for (int s = 32; s >= 1; s >>= 1){
    if (ridx < s){ red1[rg][ridx] += red1[rg][ridx+s]; red2[rg][ridx] += red2[rg][ridx+s]; }
    __syncthreads();
  }
  if (ridx == 0){
    int bb = (blockIdx.x*2) >> 12;
    atomicAdd(&stats[48 + (bb*4+rg)*2+0], red1[rg][0]);
    atomicAdd(&stats[48 + (bb*4+rg)*2+1], red2[rg][0]);
  }
}

// ---------------- edge + local avg + final output ----------------
__global__ void __launch_bounds__(256)
k_final(const float* __restrict__ epre, const float* __restrict__ logits,
        const float* __restrict__ stats, const float* __restrict__ rg_g,
        const float* __restrict__ rg_b, const float* __restrict__ pw_w,
        const float* __restrict__ pw_b, const float* __restrict__ alpha,
        float* __restrict__ outp){
  __shared__ float part[4];
  __shared__ float edge_s[2];
  int tid = threadIdx.x;
  int pixl = tid >> 7, c = tid & 127;
  int pix = blockIdx.x*2 + pixl;
  int b = pix >> 12, p = pix & 4095, yy = p >> 6, xx = p & 63;
  int g = c >> 5;
  float m = stats[48 + (b*4+g)*2]   * (1.f/NG);
  float v = stats[48 + (b*4+g)*2+1] * (1.f/NG) - m*m;
  float e = epre[(size_t)pix*128+c];
  float en = siluf((e-m)*rsqrtf(v+1e-5f)*rg_g[c] + rg_b[c]);
  float pv = en * pw_w[c];
  pv += __shfl_xor(pv,1);  pv += __shfl_xor(pv,2);  pv += __shfl_xor(pv,4);
  pv += __shfl_xor(pv,8);  pv += __shfl_xor(pv,16); pv += __shfl_xor(pv,32);
  if ((tid & 63) == 0) part[tid>>6] = pv;
  __syncthreads();
  if (tid < 2) edge_s[tid] = sigm(part[tid*2] + part[tid*2+1] + pw_b[0]);
  __syncthreads();
  if (c < 10){
    float ed = edge_s[pixl];
    int o = c;
    float lg = logits[(size_t)pix*16 + o];
    float loc = 0.f;
    for (int dy = -1; dy <= 1; dy++){
      int ny = yy+dy; if (ny < 0 || ny > 63) continue;
      for (int dx = -1; dx <= 1; dx++){
        int nx = xx+dx; if (nx < 0 || nx > 63) continue;
        loc += logits[(size_t)((b<<12)|(ny<<6)|nx)*16 + o];
      }
    }
    loc *= (1.f/9.f);
    outp[(size_t)((b*10+o)<<12) + p] = lg + alpha[0]*(1.f-ed)*(loc - lg);
  }
}

extern "C" void kernel_launch(void* const* d_in, const int* in_sizes, int n_in,
                              void* d_out, int out_size, void* d_ws, size_t ws_size,
                              hipStream_t stream){
  const float* x          = (const float*)d_in[0];
  const float* pe_w       = (const float*)d_in[1];
  const float* pe_b       = (const float*)d_in[2];
  const float* pe_gn_g    = (const float*)d_in[3];
  const float* pe_gn_b    = (const float*)d_in[4];
  const float* spa_in_w   = (const float*)d_in[5];
  const float* spa_conv_w = (const float*)d_in[6];
  const float* spa_conv_b = (const float*)d_in[7];
  const float* spa_xproj_w= (const float*)d_in[8];
  const float* spa_dt_w   = (const float*)d_in[9];
  const float* spa_dt_b   = (const float*)d_in[10];
  const float* spa_Alog   = (const float*)d_in[11];
  const float* spa_D      = (const float*)d_in[12];
  const float* spa_out_w  = (const float*)d_in[13];
  const float* spa_gn_g   = (const float*)d_in[14];
  const float* spa_gn_b   = (const float*)d_in[15];
  const float* spe_in_w   = (const float*)d_in[16];
  const float* spe_conv_w = (const float*)d_in[17];
  const float* spe_conv_b = (const float*)d_in[18];
  const float* spe_xproj_w= (const float*)d_in[19];
  const float* spe_dt_w   = (const float*)d_in[20];
  const float* spe_dt_b   = (const float*)d_in[21];
  const float* spe_Alog   = (const float*)d_in[22];
  const float* spe_D      = (const float*)d_in[23];
  const float* spe_out_w  = (const float*)d_in[24];
  const float* spe_gn_g   = (const float*)d_in[25];
  const float* spe_gn_b   = (const float*)d_in[26];
  const float* fuse_w     = (const float*)d_in[27];
  const float* cls_w      = (const float*)d_in[28];
  const float* cls_b      = (const float*)d_in[29];
  const float* ref_dw_w   = (const float*)d_in[30];
  const float* ref_gn_g   = (const float*)d_in[31];
  const float* ref_gn_b   = (const float*)d_in[32];
  const float* ref_pw_w   = (const float*)d_in[33];
  const float* ref_pw_b   = (const float*)d_in[34];
  const float* alpha      = (const float*)d_in[35];
  float* ws  = (float*)d_ws;
  float* out = (float*)d_out;

  hipMemsetAsync(ws + WS_STATS, 0, 64*sizeof(float), stream);
  k_transpose<<<64,256,0,stream>>>(pe_w, spa_in_w, spa_out_w, spa_xproj_w,
      spe_in_w, spe_xproj_w, spe_out_w,
      ws+WS_PEWT, ws+WS_INWT, ws+WS_OUTWT, ws+WS_XPWT,
      ws+WS_SPEIN, ws+WS_SPEXP, ws+WS_SPEOUT);
  k_pe<<<256,256,0,stream>>>(x, ws+WS_PEWT, pe_b, ws+WS_H1PRE, ws+WS_STATS);
  k_gnsilu<<<4096,256,0,stream>>>(ws+WS_H1PRE, ws+WS_STATS, pe_gn_g, pe_gn_b, ws+WS_H1);
  k_xz<<<256,256,0,stream>>>(ws+WS_H1, ws+WS_INWT, ws+WS_XZ);
  k_conv<<<8192,256,0,stream>>>(ws+WS_XZ, spa_conv_w, spa_conv_b, ws+WS_XC, ws+WS_ZSIL);
  k_proj<<<256,256,0,stream>>>(ws+WS_XC, ws+WS_XPWT, spa_dt_w, spa_dt_b,
      ws+WS_DELTA, ws+WS_BM, ws+WS_CM);
  k_scan1<<<2048,256,0,stream>>>(ws+WS_DELTA, ws+WS_XC, ws+WS_BM, spa_Alog, ws+WS_P, ws+WS_Q);
  k_scan2<<<32,256,0,stream>>>(ws+WS_P, ws+WS_Q, ws+WS_HS);
  k_scan3<<<2048,256,0,stream>>>(ws+WS_DELTA, ws+WS_XC, ws+WS_BM, ws+WS_CM,
      ws+WS_ZSIL, spa_Alog, spa_D, ws+WS_HS, ws+WS_Y);
  k_outproj<<<256,256,0,stream>>>(ws+WS_Y, ws+WS_OUTWT, ws+WS_H1PRE, ws+WS_STATS);
  k_spe<<<2048,256,0,stream>>>(ws+WS_H1, ws+WS_SPEIN, ws+WS_SPEXP, ws+WS_SPEOUT,
      spe_conv_w, spe_conv_b, spe_dt_w, spe_dt_b, spe_Alog, spe_D,
      ws+WS_Y2, ws+WS_STATS);
  k_fuse<<<4096,256,0,stream>>>(ws+WS_H1, ws+WS_H1PRE, ws+WS_Y2, ws+WS_STATS,
      spa_gn_g, spa_gn_b, spe_gn_g, spe_gn_b, fuse_w, cls_w, cls_b,
      ws+WS_FEAT, ws+WS_LOG);
  k_dw<<<4096,256,0,stream>>>(ws+WS_FEAT, ref_dw_w, ws+WS_Y, ws+WS_STATS);
  k_final<<<4096,256,0,stream>>>(ws+WS_Y, ws+WS_LOG, ws+WS_STATS,
      ref_gn_g, ref_gn_b, ref_pw_w, ref_pw_b, alpha, out);
  (void)in_sizes; (void)n_in; (void)out_size; (void)ws_size;
}

// Round 2
// 507.814 us; speedup vs baseline: 1.8925x; 1.8925x over previous
//
#include <hip/hip_runtime.h>
#include <math.h>

#define DEV __device__ __forceinline__

DEV float sigm(float x){ return 1.f/(1.f+__expf(-x)); }
DEV float siluf(float x){ return x * sigm(x); }
DEV float softplusf(float x){ return x > 20.f ? x : log1pf(__expf(x)); }

static constexpr float NG = 131072.0f;   // group-norm element count per (b,g): 32*64*64

// ---- workspace layout (offsets in floats) ----
static constexpr size_t WS_H1    = 0;          // B*HW*128
static constexpr size_t WS_H1PRE = 1048576;    // B*HW*128 (reused as yproj)
static constexpr size_t WS_XC    = 2097152;    // B*HW*256
static constexpr size_t WS_ZSIL  = 4194304;    // B*HW*256
static constexpr size_t WS_XZ    = 6291456;    // B*HW*512  (xz; later delta/Bm/Cm/logits)
static constexpr size_t WS_DELTA = 6291456;    // B*HW*256
static constexpr size_t WS_BM    = 8388608;    // B*HW*16
static constexpr size_t WS_CM    = 8519680;    // B*HW*16
static constexpr size_t WS_LOG   = 8650752;    // B*HW*16 (logits, stride 16, 10 used)
static constexpr size_t WS_Y     = 10485760;   // B*HW*256 (y; later e_pre; pre-scan: pe partials)
static constexpr size_t WS_P     = 12582912;   // B*64*256*16 (after scan3: dw partials)
static constexpr size_t WS_Q     = 13107200;   // (after scan3: spe partials)
static constexpr size_t WS_HS    = 13631488;   // (after scan3: outproj partials)
static constexpr size_t WS_Y2    = 14155776;   // B*HW*128
static constexpr size_t WS_FEAT  = 15204352;   // B*HW*128
static constexpr size_t WS_STATS = 16252928;   // 64 floats: pe@0 spa@16 spe@32 ref@48
static constexpr size_t WS_PEWT  = 16253056;   // 128*128
static constexpr size_t WS_INWT  = WS_PEWT  + 16384;  // 128*512
static constexpr size_t WS_OUTWT = WS_INWT  + 65536;  // 256*128
static constexpr size_t WS_XPWT  = WS_OUTWT + 32768;  // 256*40
static constexpr size_t WS_SPEIN = WS_XPWT  + 10240;  // 32*128
static constexpr size_t WS_SPEXP = WS_SPEIN + 4096;   // 64*34
static constexpr size_t WS_SPEOUT= WS_SPEXP + 2176;   // 64*32

// ---------------- partial-stats reduction: grid = 16 (b in 0..1, j in 0..7) ----
// part layout: [block][8] with blocks [0,half) = batch 0, [half,2*half) = batch 1.
__global__ void __launch_bounds__(256)
k_red(const float* __restrict__ part, float* __restrict__ outS, int half){
  __shared__ float red[4];
  int b = blockIdx.x >> 3, j = blockIdx.x & 7;
  float s = 0.f;
  for (int i = b*half + threadIdx.x; i < (b+1)*half; i += 256)
    s += part[(size_t)i*8 + j];
  s += __shfl_xor(s,1); s += __shfl_xor(s,2); s += __shfl_xor(s,4);
  s += __shfl_xor(s,8); s += __shfl_xor(s,16); s += __shfl_xor(s,32);
  if ((threadIdx.x & 63) == 0) red[threadIdx.x>>6] = s;
  __syncthreads();
  if (threadIdx.x == 0) outS[b*8+j] = red[0]+red[1]+red[2]+red[3];
}

// ---------------- transpose weights ----------------
__global__ void __launch_bounds__(256)
k_transpose(const float* __restrict__ pe_w, const float* __restrict__ in_w,
            const float* __restrict__ out_w, const float* __restrict__ xp_w,
            const float* __restrict__ spe_in, const float* __restrict__ spe_xp,
            const float* __restrict__ spe_out,
            float* __restrict__ peT, float* __restrict__ inT,
            float* __restrict__ outT, float* __restrict__ xpT,
            float* __restrict__ speInT, float* __restrict__ speXpT,
            float* __restrict__ speOutT){
  int i0 = blockIdx.x*256 + threadIdx.x;
  int nt = gridDim.x*256;
  for (int k = i0; k < 128*128; k += nt){ int r = k >> 7, c = k & 127; peT[c*128 + r] = pe_w[k]; }
  for (int k = i0; k < 512*128; k += nt){ int r = k >> 7, c = k & 127; inT[c*512 + r] = in_w[k]; }
  for (int k = i0; k < 128*256; k += nt){ int r = k >> 8, c = k & 255; outT[c*128 + r] = out_w[k]; }
  for (int k = i0; k < 40*256;  k += nt){ int r = k >> 8, c = k & 255; xpT[c*40 + r] = xp_w[k]; }
  for (int k = i0; k < 128*32;  k += nt){ int r = k >> 5, c = k & 31;  speInT[c*128 + r] = spe_in[k]; }
  for (int k = i0; k < 34*64;   k += nt){ int r = k >> 6, c = k & 63;  speXpT[c*34 + r] = spe_xp[k]; }
  for (int k = i0; k < 32*64;   k += nt){ int r = k >> 6, c = k & 63;  speOutT[c*32 + r] = spe_out[k]; }
}

// ---------------- pe 1x1 conv + GN partial stats ----------------
__global__ void __launch_bounds__(256)
k_pe(const float* __restrict__ x, const float* __restrict__ peT,
     const float* __restrict__ pe_b, float* __restrict__ h1pre,
     float* __restrict__ part){
  __shared__ float xs[128][33];
  __shared__ float red1[4][64], red2[4][64];
  int tid = threadIdx.x;
  int m0 = blockIdx.x * 32;          // global pixel base (B*HW)
  int b = m0 >> 12, pl = m0 & 4095;
  for (int i = tid; i < 32*128; i += 256){
    int t = i >> 7, c = i & 127;
    xs[c][t] = x[(size_t)(b*128 + c)*4096 + pl + t];
  }
  __syncthreads();
  int o = tid & 127, half = tid >> 7;
  float acc[16];
  #pragma unroll
  for (int t = 0; t < 16; t++) acc[t] = 0.f;
  for (int c = 0; c < 128; c++){
    float wv = peT[c*128 + o];
    const float* xr = &xs[c][half*16];
    #pragma unroll
    for (int t = 0; t < 16; t++) acc[t] += wv * xr[t];
  }
  float bo = pe_b[o];
  float s1 = 0.f, s2 = 0.f;
  for (int t = 0; t < 16; t++){
    float vv = acc[t] + bo;
    s1 += vv; s2 += vv*vv;
    h1pre[(size_t)(m0 + half*16 + t)*128 + o] = vv;
  }
  int g = o >> 5, idx = (o & 31) | (half << 5);
  red1[g][idx] = s1; red2[g][idx] = s2;
  __syncthreads();
  int rg = tid >> 6, ridx = tid & 63;
  for (int s = 32; s >= 1; s >>= 1){
    if (ridx < s){ red1[rg][ridx] += red1[rg][ridx+s]; red2[rg][ridx] += red2[rg][ridx+s]; }
    __syncthreads();
  }
  if (ridx == 0){
    part[(size_t)blockIdx.x*8 + rg*2+0] = red1[rg][0];
    part[(size_t)blockIdx.x*8 + rg*2+1] = red2[rg][0];
  }
}

// ---------------- GN + silu elementwise (pe) ----------------
__global__ void __launch_bounds__(256)
k_gnsilu(const float* __restrict__ pre, const float* __restrict__ stats,
         const float* __restrict__ gw, const float* __restrict__ gb,
         float* __restrict__ outb){
  int idx = blockIdx.x*256 + threadIdx.x;
  int c = idx & 127; int pix = idx >> 7; int b = pix >> 12; int g = c >> 5;
  float s1 = stats[(b*4+g)*2], s2 = stats[(b*4+g)*2+1];
  float m = s1 * (1.f/NG);
  float v = s2 * (1.f/NG) - m*m;
  float xn = (pre[idx] - m) * rsqrtf(v + 1e-5f);
  float val = xn * gw[c] + gb[c];
  outb[idx] = siluf(val);
}

// ---------------- spa in-proj: xz = h1 @ in_w.T ----------------
__global__ void __launch_bounds__(256)
k_xz(const float* __restrict__ h1, const float* __restrict__ inT,
     float* __restrict__ xz){
  __shared__ float xs[128][33];
  int tid = threadIdx.x;
  int m0 = blockIdx.x * 32;
  for (int i = tid; i < 32*128; i += 256){
    int t = i >> 7, c = i & 127;
    xs[c][t] = h1[(size_t)(m0 + t)*128 + c];
  }
  __syncthreads();
  float acc0[32], acc1[32];
  #pragma unroll
  for (int t = 0; t < 32; t++){ acc0[t]=0.f; acc1[t]=0.f; }
  int o = tid;
  for (int c = 0; c < 128; c++){
    float w0 = inT[c*512 + o];
    float w1 = inT[c*512 + o + 256];
    #pragma unroll
    for (int t = 0; t < 32; t++){
      float a = xs[c][t];
      acc0[t] += w0*a; acc1[t] += w1*a;
    }
  }
  for (int t = 0; t < 32; t++){
    xz[(size_t)(m0+t)*512 + o]       = acc0[t];
    xz[(size_t)(m0+t)*512 + o + 256] = acc1[t];
  }
}

// ---------------- causal depthwise conv K=4 + silu; z->silu(z) ----------------
__global__ void __launch_bounds__(256)
k_conv(const float* __restrict__ xz, const float* __restrict__ cw,
       const float* __restrict__ cb, float* __restrict__ xc,
       float* __restrict__ zsil){
  int idx = blockIdx.x*256 + threadIdx.x;   // B*4096*256
  int d = idx & 255;
  int l = (idx >> 8) & 4095;
  int b = idx >> 20;
  float v = cb[d];
  #pragma unroll
  for (int k = 0; k < 4; k++){
    int ls = l - 3 + k;
    if (ls >= 0) v += xz[(size_t)(b*4096 + ls)*512 + d] * cw[d*4 + k];
  }
  xc[idx] = siluf(v);
  float z = xz[(size_t)(b*4096 + l)*512 + 256 + d];
  zsil[idx] = siluf(z);
}

// ---------------- x-proj (dt,B,C) + delta=softplus(dt@dtw.T+dtb) ----------------
__global__ void __launch_bounds__(256)
k_proj(const float* __restrict__ xc, const float* __restrict__ xpT,
       const float* __restrict__ dtw, const float* __restrict__ dtb,
       float* __restrict__ delta, float* __restrict__ Bm, float* __restrict__ Cm){
  __shared__ float xt[32][260];
  __shared__ float pr[32][40];
  int tid = threadIdx.x;
  int m0 = blockIdx.x * 32;
  for (int i = tid; i < 32*256; i += 256){
    int t = i >> 8, d = i & 255;
    xt[t][d] = xc[(size_t)(m0+t)*256 + d];
  }
  __syncthreads();
  {
    int t = tid >> 3, j0 = tid & 7;
    float a0=0.f,a1=0.f,a2=0.f,a3=0.f,a4=0.f;
    for (int d = 0; d < 256; d++){
      float xv = xt[t][d];
      const float* wp = &xpT[d*40 + j0];
      a0 += xv*wp[0]; a1 += xv*wp[8]; a2 += xv*wp[16]; a3 += xv*wp[24]; a4 += xv*wp[32];
    }
    pr[t][j0] = a0; pr[t][j0+8] = a1; pr[t][j0+16] = a2; pr[t][j0+24] = a3; pr[t][j0+32] = a4;
  }
  __syncthreads();
  {
    int d = tid;
    float w[8];
    #pragma unroll
    for (int r = 0; r < 8; r++) w[r] = dtw[d*8+r];
    float bd = dtb[d];
    for (int t = 0; t < 32; t++){
      float val = bd;
      #pragma unroll
      for (int r = 0; r < 8; r++) val += pr[t][r]*w[r];
      delta[(size_t)(m0+t)*256 + d] = softplusf(val);
    }
  }
  for (int i = tid; i < 512; i += 256){
    int t = i >> 4, n = i & 15;
    Bm[(size_t)(m0+t)*16 + n] = pr[t][8+n];
    Cm[(size_t)(m0+t)*16 + n] = pr[t][24+n];
  }
}

// ---------------- chunked scan phase 1: per-chunk (P,Q) ----------------
__global__ void __launch_bounds__(256)
k_scan1(const float* __restrict__ delta, const float* __restrict__ xc,
        const float* __restrict__ Bm, const float* __restrict__ Alog,
        float* __restrict__ P, float* __restrict__ Q){
  __shared__ float sd[64][16], sx[64][16], sb[64][16];
  int blk = blockIdx.x;            // 2*64*16
  int b = blk >> 10;
  int chunk = (blk >> 4) & 63;
  int dblk = blk & 15;
  int tid = threadIdx.x;
  size_t rowbase = (size_t)(b*4096 + chunk*64);
  for (int i = tid; i < 64*16; i += 256){
    int ii = i >> 4, dd = i & 15;
    sd[ii][dd] = delta[(rowbase + ii)*256 + dblk*16 + dd];
    sx[ii][dd] = xc  [(rowbase + ii)*256 + dblk*16 + dd];
    sb[ii][dd] = Bm  [(rowbase + ii)*16 + dd];
  }
  int dl = tid >> 4, n = tid & 15;
  int d = dblk*16 + dl;
  float An = -__expf(Alog[d*16 + n]);
  __syncthreads();
  float Pv = 1.f, Qv = 0.f;
  for (int i = 0; i < 64; i++){
    float dv = sd[i][dl];
    float a = __expf(dv * An);
    Qv = a*Qv + dv * sb[i][n] * sx[i][dl];
    Pv *= a;
  }
  size_t o = (size_t)(b*64+chunk)*4096 + dblk*256 + tid;
  P[o] = Pv; Q[o] = Qv;
}

// ---------------- chunked scan phase 2: cross-chunk sequential ----------------
__global__ void __launch_bounds__(256)
k_scan2(const float* __restrict__ P, const float* __restrict__ Q,
        float* __restrict__ hs){
  int gid = blockIdx.x*256 + threadIdx.x;  // 8192 = B*256*16
  int b = gid >> 12, dn = gid & 4095;
  float h = 0.f;
  for (int ch = 0; ch < 64; ch++){
    size_t idx = (size_t)(b*64 + ch)*4096 + dn;
    hs[idx] = h;
    h = P[idx]*h + Q[idx];
  }
}

// ---------------- chunked scan phase 3: replay + y ----------------
__global__ void __launch_bounds__(256)
k_scan3(const float* __restrict__ delta, const float* __restrict__ xc,
        const float* __restrict__ Bm, const float* __restrict__ Cm,
        const float* __restrict__ zsil, const float* __restrict__ Alog,
        const float* __restrict__ Dv, const float* __restrict__ hs,
        float* __restrict__ y){
  __shared__ float sd[64][16], sx[64][16], sb[64][16], sc[64][16], sz[64][16], yt[64][16];
  int blk = blockIdx.x;
  int b = blk >> 10;
  int chunk = (blk >> 4) & 63;
  int dblk = blk & 15;
  int tid = threadIdx.x;
  size_t rowbase = (size_t)(b*4096 + chunk*64);
  for (int i = tid; i < 64*16; i += 256){
    int ii = i >> 4, dd = i & 15;
    sd[ii][dd] = delta[(rowbase + ii)*256 + dblk*16 + dd];
    sx[ii][dd] = xc  [(rowbase + ii)*256 + dblk*16 + dd];
    sz[ii][dd] = zsil[(rowbase + ii)*256 + dblk*16 + dd];
    sb[ii][dd] = Bm  [(rowbase + ii)*16 + dd];
    sc[ii][dd] = Cm  [(rowbase + ii)*16 + dd];
  }
  int dl = tid >> 4, n = tid & 15;
  int d = dblk*16 + dl;
  float An = -__expf(Alog[d*16 + n]);
  float h = hs[(size_t)(b*64+chunk)*4096 + dblk*256 + tid];
  float Dd = Dv[d];
  __syncthreads();
  for (int i = 0; i < 64; i++){
    float dv = sd[i][dl], xv = sx[i][dl];
    float a = __expf(dv * An);
    h = a*h + dv * sb[i][n] * xv;
    float ctr = h * sc[i][n];
    ctr += __shfl_xor(ctr, 1);
    ctr += __shfl_xor(ctr, 2);
    ctr += __shfl_xor(ctr, 4);
    ctr += __shfl_xor(ctr, 8);
    if (n == 0) yt[i][dl] = (ctr + Dd*xv) * sz[i][dl];
  }
  __syncthreads();
  for (int i = tid; i < 1024; i += 256){
    int ii = i >> 4, dd = i & 15;
    y[(rowbase + ii)*256 + dblk*16 + dd] = yt[ii][dd];
  }
}

// ---------------- spa out-proj + GN partial stats ----------------
__global__ void __launch_bounds__(256)
k_outproj(const float* __restrict__ y, const float* __restrict__ outT,
          float* __restrict__ yproj, float* __restrict__ part){
  __shared__ float ytile[256][33];
  __shared__ float red1[4][64], red2[4][64];
  int tid = threadIdx.x;
  int m0 = blockIdx.x * 32;
  for (int i = tid; i < 32*256; i += 256){
    int t = i >> 8, d = i & 255;
    ytile[d][t] = y[(size_t)(m0+t)*256 + d];
  }
  __syncthreads();
  int o = tid & 127, half = tid >> 7;
  float acc[16];
  #pragma unroll
  for (int t = 0; t < 16; t++) acc[t] = 0.f;
  for (int d = 0; d < 256; d++){
    float wv = outT[d*128 + o];
    const float* yr = &ytile[d][half*16];
    #pragma unroll
    for (int t = 0; t < 16; t++) acc[t] += wv * yr[t];
  }
  float s1 = 0.f, s2 = 0.f;
  for (int t = 0; t < 16; t++){
    float vv = acc[t];
    s1 += vv; s2 += vv*vv;
    yproj[(size_t)(m0 + half*16 + t)*128 + o] = vv;
  }
  int g = o >> 5, idx = (o & 31) | (half << 5);
  red1[g][idx] = s1; red2[g][idx] = s2;
  __syncthreads();
  int rg = tid >> 6, ridx = tid & 63;
  for (int s = 32; s >= 1; s >>= 1){
    if (ridx < s){ red1[rg][ridx] += red1[rg][ridx+s]; red2[rg][ridx] += red2[rg][ridx+s]; }
    __syncthreads();
  }
  if (ridx == 0){
    part[(size_t)blockIdx.x*8 + rg*2+0] = red1[rg][0];
    part[(size_t)blockIdx.x*8 + rg*2+1] = red2[rg][0];
  }
}

// ---------------- spectral mamba: one wave per pixel ----------------
__global__ void __launch_bounds__(256)
k_spe(const float* __restrict__ h1, const float* __restrict__ speInT,
      const float* __restrict__ speXpT, const float* __restrict__ speOutT,
      const float* __restrict__ conv_w, const float* __restrict__ conv_b,
      const float* __restrict__ dt_w, const float* __restrict__ dt_b,
      const float* __restrict__ Alog, const float* __restrict__ Dvec,
      float* __restrict__ y2, float* __restrict__ part){
  __shared__ float w_inT[32][128];
  __shared__ float w_xpT[64][34];
  __shared__ float w_outT[64][32];
  __shared__ float w_dtw[64][2];
  __shared__ float w_cw[64][4];
  __shared__ float w_cb[64], w_db[64], w_D[64];
  __shared__ float w_At[16][64];   // [n][d] = -exp(Alog[d][n])
  __shared__ float s_in[4][128];
  __shared__ float s_xc[4][4][64];
  __shared__ float s_pr[4][4][34];
  __shared__ float s_y[4][4][64];
  __shared__ float bst[8];
  int tid = threadIdx.x;
  for (int i = tid; i < 4096; i += 256) ((float*)w_inT)[i] = speInT[i];
  for (int i = tid; i < 64*34; i += 256) ((float*)w_xpT)[i] = speXpT[i];
  for (int i = tid; i < 2048; i += 256) ((float*)w_outT)[i] = speOutT[i];
  if (tid < 128) ((float*)w_dtw)[tid] = dt_w[tid];
  ((float*)w_cw)[tid] = conv_w[tid];
  if (tid < 64){ w_cb[tid] = conv_b[tid]; w_db[tid] = dt_b[tid]; w_D[tid] = Dvec[tid]; }
  for (int i = tid; i < 1024; i += 256){
    int d = i & 63, n = i >> 6;
    w_At[n][d] = -__expf(Alog[d*16 + n]);
  }
  if (tid < 8) bst[tid] = 0.f;
  __syncthreads();
  int w = tid >> 6, lane = tid & 63;
  int pix = blockIdx.x*4 + w;
  // phase 0: load pixel channels
  {
    const float2* h2 = (const float2*)(h1 + (size_t)pix*128);
    float2 v = h2[lane];
    s_in[w][2*lane] = v.x; s_in[w][2*lane+1] = v.y;
  }
  // phase 1: in-proj (x part in regs for own d=lane, z part too)
  float xpr[4], zr[4], xcr[4], dlr[4];
  #pragma unroll
  for (int l = 0; l < 4; l++){
    float acc0 = 0.f, acc1 = 0.f;
    #pragma unroll
    for (int c = 0; c < 32; c++){
      float sv = s_in[w][l*32+c];
      acc0 += sv * w_inT[c][lane];
      acc1 += sv * w_inT[c][64+lane];
    }
    xpr[l] = acc0; zr[l] = acc1;
  }
  // phase 2: causal conv K=4 + silu (depthwise over l, own lane only)
  {
    int d = lane;
    float cb = w_cb[d];
    #pragma unroll
    for (int l = 0; l < 4; l++){
      float v = cb;
      #pragma unroll
      for (int k = 0; k < 4; k++){
        int ls = l - 3 + k;
        if (ls >= 0) v += xpr[ls] * w_cw[d][k];
      }
      float sx = siluf(v);
      s_xc[w][l][d] = sx;
      xcr[l] = sx;
    }
  }
  // phase 3: x-proj (34 outputs, lanes<34)
  if (lane < 34){
    #pragma unroll
    for (int l = 0; l < 4; l++){
      float acc = 0.f;
      for (int dd = 0; dd < 64; dd++) acc += s_xc[w][l][dd] * w_xpT[dd][lane];
      s_pr[w][l][lane] = acc;
    }
  }
  // phase 3b: delta
  {
    int d = lane;
    float w0 = w_dtw[d][0], w1 = w_dtw[d][1], bdd = w_db[d];
    #pragma unroll
    for (int l = 0; l < 4; l++)
      dlr[l] = softplusf(bdd + s_pr[w][l][0]*w0 + s_pr[w][l][1]*w1);
  }
  // phase 4: scan (L=4, n in registers)
  {
    int d = lane;
    float h[16];
    #pragma unroll
    for (int n = 0; n < 16; n++) h[n] = 0.f;
    float Dd = w_D[d];
    #pragma unroll
    for (int l = 0; l < 4; l++){
      float dv = dlr[l], xv = xcr[l];
      float ys = 0.f;
      #pragma unroll
      for (int n = 0; n < 16; n++){
        float a = __expf(dv * w_At[n][d]);
        h[n] = a*h[n] + dv * s_pr[w][l][2+n] * xv;
        ys += h[n] * s_pr[w][l][18+n];
      }
      s_y[w][l][d] = (ys + Dd*xv) * siluf(zr[l]);
    }
  }
  // phase 5: out-proj + GN stats (group of channel l*32+c2 is l)
  #pragma unroll
  for (int pass = 0; pass < 2; pass++){
    int l = (lane >> 5) + pass*2;
    int c2 = lane & 31;
    float acc = 0.f;
    for (int dd = 0; dd < 64; dd++) acc += s_y[w][l][dd] * w_outT[dd][c2];
    y2[(size_t)pix*128 + l*32 + c2] = acc;
    float a1 = acc, a2 = acc*acc;
    a1 += __shfl_xor(a1,1);  a2 += __shfl_xor(a2,1);
    a1 += __shfl_xor(a1,2);  a2 += __shfl_xor(a2,2);
    a1 += __shfl_xor(a1,4);  a2 += __shfl_xor(a2,4);
    a1 += __shfl_xor(a1,8);  a2 += __shfl_xor(a2,8);
    a1 += __shfl_xor(a1,16); a2 += __shfl_xor(a2,16);
    if ((lane & 31) == 0){
      atomicAdd(&bst[l*2+0], a1);   // LDS atomics: cheap
      atomicAdd(&bst[l*2+1], a2);
    }
  }
  __syncthreads();
  if (tid < 8) part[(size_t)blockIdx.x*8 + tid] = bst[tid];
}

// ---------------- fuse: GN(spa)+GN(spe)+h1 -> feat, logits ----------------
__global__ void __launch_bounds__(256)
k_fuse(const float* __restrict__ h1, const float* __restrict__ yproj,
       const float* __restrict__ y2, const float* __restrict__ stats,
       const float* __restrict__ spa_g, const float* __restrict__ spa_b,
       const float* __restrict__ spe_g, const float* __restrict__ spe_b,
       const float* __restrict__ fuse_w, const float* __restrict__ cls_w,
       const float* __restrict__ cls_b, float* __restrict__ feat,
       float* __restrict__ logits){
  __shared__ float ft[2][128];
  int tid = threadIdx.x;
  int pixl = tid >> 7, c = tid & 127;
  int pix = blockIdx.x*2 + pixl;
  int b = pix >> 12, g = c >> 5;
  float m1 = stats[16 + (b*4+g)*2]   * (1.f/NG);
  float v1 = stats[16 + (b*4+g)*2+1] * (1.f/NG) - m1*m1;
  float m2 = stats[32 + (b*4+g)*2]   * (1.f/NG);
  float v2 = stats[32 + (b*4+g)*2+1] * (1.f/NG) - m2*m2;
  float h = h1[(size_t)pix*128 + c];
  float sa = siluf((yproj[(size_t)pix*128+c] - m1)*rsqrtf(v1+1e-5f)*spa_g[c] + spa_b[c]) + h;
  float sp = h + siluf((y2[(size_t)pix*128+c] - m2)*rsqrtf(v2+1e-5f)*spe_g[c] + spe_b[c]);
  float e0 = __expf(fuse_w[0]), e1 = __expf(fuse_w[1]);
  float w0 = e0/(e0+e1), w1 = e1/(e0+e1);
  float f = sa*w0 + sp*w1 + h;
  feat[(size_t)pix*128+c] = f;
  ft[pixl][c] = f;
  __syncthreads();
  if (tid < 20){
    int pl = (tid >= 10) ? 1 : 0;
    int o = tid - pl*10;
    float acc = cls_b[o];
    for (int cc = 0; cc < 128; cc++) acc += ft[pl][cc]*cls_w[o*128+cc];
    logits[(size_t)(blockIdx.x*2 + pl)*16 + o] = acc;
  }
}

// ---------------- depthwise 3x3 on feat + GN partial stats ----------------
__global__ void __launch_bounds__(256)
k_dw(const float* __restrict__ feat, const float* __restrict__ dww,
     float* __restrict__ epre, float* __restrict__ part){
  __shared__ float red1[4][64], red2[4][64];
  int tid = threadIdx.x;
  int pixl = tid >> 7, c = tid & 127;
  int pix = blockIdx.x*2 + pixl;
  int b = pix >> 12, p = pix & 4095, yy = p >> 6, xx = p & 63;
  float acc = 0.f;
  for (int dy = -1; dy <= 1; dy++){
    int ny = yy + dy; if (ny < 0 || ny > 63) continue;
    for (int dx = -1; dx <= 1; dx++){
      int nx = xx + dx; if (nx < 0 || nx > 63) continue;
      acc += feat[(size_t)((b<<12)|(ny<<6)|nx)*128 + c] * dww[c*9 + (dy+1)*3 + (dx+1)];
    }
  }
  epre[(size_t)pix*128 + c] = acc;
  int g = c >> 5;
  int idx = (c & 31) | (pixl << 5);
  red1[g][idx] = acc; red2[g][idx] = acc*acc;
  __syncthreads();
  int rg = tid >> 6, ridx = tid & 63;
  for (int s = 32; s >= 1; s >>= 1){
    if (ridx < s){ red1[rg][ridx] += red1[rg][ridx+s]; red2[rg][ridx] += red2[rg][ridx+s]; }
    __syncthreads();
  }
  if (ridx == 0){
    part[(size_t)blockIdx.x*8 + rg*2+0] = red1[rg][0];
    part[(size_t)blockIdx.x*8 + rg*2+1] = red2[rg][0];
  }
}

// ---------------- edge + local avg + final output ----------------
__global__ void __launch_bounds__(256)
k_final(const float* __restrict__ epre, const float* __restrict__ logits,
        const float* __restrict__ stats, const float* __restrict__ rg_g,
        const float* __restrict__ rg_b, const float* __restrict__ pw_w,
        const float* __restrict__ pw_b, const float* __restrict__ alpha,
        float* __restrict__ outp){
  __shared__ float part[4];
  __shared__ float edge_s[2];
  int tid = threadIdx.x;
  int pixl = tid >> 7, c = tid & 127;
  int pix = blockIdx.x*2 + pixl;
  int b = pix >> 12, p = pix & 4095, yy = p >> 6, xx = p & 63;
  int g = c >> 5;
  float m = stats[48 + (b*4+g)*2]   * (1.f/NG);
  float v = stats[48 + (b*4+g)*2+1] * (1.f/NG) - m*m;
  float e = epre[(size_t)pix*128+c];
  float en = siluf((e-m)*rsqrtf(v+1e-5f)*rg_g[c] + rg_b[c]);
  float pv = en * pw_w[c];
  pv += __shfl_xor(pv,1);  pv += __shfl_xor(pv,2);  pv += __shfl_xor(pv,4);
  pv += __shfl_xor(pv,8);  pv += __shfl_xor(pv,16); pv += __shfl_xor(pv,32);
  if ((tid & 63) == 0) part[tid>>6] = pv;
  __syncthreads();
  if (tid < 2) edge_s[tid] = sigm(part[tid*2] + part[tid*2+1] + pw_b[0]);
  __syncthreads();
  if (c < 10){
    float ed = edge_s[pixl];
    int o = c;
    float lg = logits[(size_t)pix*16 + o];
    float loc = 0.f;
    for (int dy = -1; dy <= 1; dy++){
      int ny = yy+dy; if (ny < 0 || ny > 63) continue;
      for (int dx = -1; dx <= 1; dx++){
        int nx = xx+dx; if (nx < 0 || nx > 63) continue;
        loc += logits[(size_t)((b<<12)|(ny<<6)|nx)*16 + o];
      }
    }
    loc *= (1.f/9.f);
    outp[(size_t)((b*10+o)<<12) + p] = lg + alpha[0]*(1.f-ed)*(loc - lg);
  }
}

extern "C" void kernel_launch(void* const* d_in, const int* in_sizes, int n_in,
                              void* d_out, int out_size, void* d_ws, size_t ws_size,
                              hipStream_t stream){
  const float* x          = (const float*)d_in[0];
  const float* pe_w       = (const float*)d_in[1];
  const float* pe_b       = (const float*)d_in[2];
  const float* pe_gn_g    = (const float*)d_in[3];
  const float* pe_gn_b    = (const float*)d_in[4];
  const float* spa_in_w   = (const float*)d_in[5];
  const float* spa_conv_w = (const float*)d_in[6];
  const float* spa_conv_b = (const float*)d_in[7];
  const float* spa_xproj_w= (const float*)d_in[8];
  const float* spa_dt_w   = (const float*)d_in[9];
  const float* spa_dt_b   = (const float*)d_in[10];
  const float* spa_Alog   = (const float*)d_in[11];
  const float* spa_D      = (const float*)d_in[12];
  const float* spa_out_w  = (const float*)d_in[13];
  const float* spa_gn_g   = (const float*)d_in[14];
  const float* spa_gn_b   = (const float*)d_in[15];
  const float* spe_in_w   = (const float*)d_in[16];
  const float* spe_conv_w = (const float*)d_in[17];
  const float* spe_conv_b = (const float*)d_in[18];
  const float* spe_xproj_w= (const float*)d_in[19];
  const float* spe_dt_w   = (const float*)d_in[20];
  const float* spe_dt_b   = (const float*)d_in[21];
  const float* spe_Alog   = (const float*)d_in[22];
  const float* spe_D      = (const float*)d_in[23];
  const float* spe_out_w  = (const float*)d_in[24];
  const float* spe_gn_g   = (const float*)d_in[25];
  const float* spe_gn_b   = (const float*)d_in[26];
  const float* fuse_w     = (const float*)d_in[27];
  const float* cls_w      = (const float*)d_in[28];
  const float* cls_b      = (const float*)d_in[29];
  const float* ref_dw_w   = (const float*)d_in[30];
  const float* ref_gn_g   = (const float*)d_in[31];
  const float* ref_gn_b   = (const float*)d_in[32];
  const float* ref_pw_w   = (const float*)d_in[33];
  const float* ref_pw_b   = (const float*)d_in[34];
  const float* alpha      = (const float*)d_in[35];
  float* ws  = (float*)d_ws;
  float* out = (float*)d_out;

  // partials buffers reuse scan scratch (dead at the time of use):
  float* partPE  = ws + WS_Y;    // k_pe runs before scan3 writes Y
  float* partSPA = ws + WS_HS;   // k_outproj runs after scan3 (HS dead)
  float* partSPE = ws + WS_Q;    // k_spe runs after scan3 (Q dead)
  float* partDW  = ws + WS_P;    // k_dw runs after scan3 (P dead)

  k_transpose<<<64,256,0,stream>>>(pe_w, spa_in_w, spa_out_w, spa_xproj_w,
      spe_in_w, spe_xproj_w, spe_out_w,
      ws+WS_PEWT, ws+WS_INWT, ws+WS_OUTWT, ws+WS_XPWT,
      ws+WS_SPEIN, ws+WS_SPEXP, ws+WS_SPEOUT);
  k_pe<<<256,256,0,stream>>>(x, ws+WS_PEWT, pe_b, ws+WS_H1PRE, partPE);
  k_red<<<16,256,0,stream>>>(partPE, ws+WS_STATS+0, 128);
  k_gnsilu<<<4096,256,0,stream>>>(ws+WS_H1PRE, ws+WS_STATS, pe_gn_g, pe_gn_b, ws+WS_H1);
  k_xz<<<256,256,0,stream>>>(ws+WS_H1, ws+WS_INWT, ws+WS_XZ);
  k_conv<<<8192,256,0,stream>>>(ws+WS_XZ, spa_conv_w, spa_conv_b, ws+WS_XC, ws+WS_ZSIL);
  k_proj<<<256,256,0,stream>>>(ws+WS_XC, ws+WS_XPWT, spa_dt_w, spa_dt_b,
      ws+WS_DELTA, ws+WS_BM, ws+WS_CM);
  k_scan1<<<2048,256,0,stream>>>(ws+WS_DELTA, ws+WS_XC, ws+WS_BM, spa_Alog, ws+WS_P, ws+WS_Q);
  k_scan2<<<32,256,0,stream>>>(ws+WS_P, ws+WS_Q, ws+WS_HS);
  k_scan3<<<2048,256,0,stream>>>(ws+WS_DELTA, ws+WS_XC, ws+WS_BM, ws+WS_CM,
      ws+WS_ZSIL, spa_Alog, spa_D, ws+WS_HS, ws+WS_Y);
  k_outproj<<<256,256,0,stream>>>(ws+WS_Y, ws+WS_OUTWT, ws+WS_H1PRE, partSPA);
  k_red<<<16,256,0,stream>>>(partSPA, ws+WS_STATS+16, 128);
  k_spe<<<2048,256,0,stream>>>(ws+WS_H1, ws+WS_SPEIN, ws+WS_SPEXP, ws+WS_SPEOUT,
      spe_conv_w, spe_conv_b, spe_dt_w, spe_dt_b, spe_Alog, spe_D,
      ws+WS_Y2, partSPE);
  k_red<<<16,256,0,stream>>>(partSPE, ws+WS_STATS+32, 1024);
  k_fuse<<<4096,256,0,stream>>>(ws+WS_H1, ws+WS_H1PRE, ws+WS_Y2, ws+WS_STATS,
      spa_gn_g, spa_gn_b, spe_gn_g, spe_gn_b, fuse_w, cls_w, cls_b,
      ws+WS_FEAT, ws+WS_LOG);
  k_dw<<<4096,256,0,stream>>>(ws+WS_FEAT, ref_dw_w, ws+WS_Y, partDW);
  k_red<<<16,256,0,stream>>>(partDW, ws+WS_STATS+48, 2048);
  k_final<<<4096,256,0,stream>>>(ws+WS_Y, ws+WS_LOG, ws+WS_STATS,
      ref_gn_g, ref_gn_b, ref_pw_w, ref_pw_b, alpha, out);
  (void)in_sizes; (void)n_in; (void)out_size; (void)ws_size;
}

// Round 3
// 461.416 us; speedup vs baseline: 2.0828x; 1.1006x over previous
//
#include <hip/hip_runtime.h>
#include <math.h>

#define DEV __device__ __forceinline__

DEV float sigm(float x){ return 1.f/(1.f+__expf(-x)); }
DEV float siluf(float x){ return x * sigm(x); }
DEV float softplusf(float x){ return x > 20.f ? x : log1pf(__expf(x)); }

static constexpr float NG = 131072.0f;   // group-norm element count per (b,g): 32*64*64

// ---- workspace layout (offsets in floats) ----
static constexpr size_t WS_H1    = 0;          // B*HW*128
static constexpr size_t WS_H1PRE = 1048576;    // B*HW*128 (reused as yproj)
static constexpr size_t WS_XC    = 2097152;    // B*HW*256 (spa xc; later spe xc2[tok][64])
static constexpr size_t WS_ZSIL  = 4194304;    // B*HW*256 (spa zsil; later spe xc2T[64][tok])
static constexpr size_t WS_XZ    = 6291456;    // B*HW*512  (xz; later delta; later spe zsil2)
static constexpr size_t WS_DELTA = 6291456;    // B*HW*256
static constexpr size_t WS_BM    = 8388608;    // B*HW*16 (later spe proj[tok][36])
static constexpr size_t WS_CM    = 8519680;    // B*HW*16
static constexpr size_t WS_LOG   = 8650752;    // B*HW*16 (logits, stride 16, 10 used)
static constexpr size_t WS_Y     = 10485760;   // B*HW*256 (y; pe partials; spe yg; later e_pre)
static constexpr size_t WS_P     = 12582912;   // B*64*256*16 (after scan3: dw partials)
static constexpr size_t WS_Q     = 13107200;   // (after scan3: spe partials)
static constexpr size_t WS_HS    = 13631488;   // (after scan3: outproj partials)
static constexpr size_t WS_Y2    = 14155776;   // B*HW*128
static constexpr size_t WS_FEAT  = 15204352;   // B*HW*128
static constexpr size_t WS_STATS = 16252928;   // 64 floats: pe@0 spa@16 spe@32 ref@48
static constexpr size_t WS_PEWT  = 16253056;   // 128*128
static constexpr size_t WS_INWT  = WS_PEWT  + 16384;  // 128*512
static constexpr size_t WS_OUTWT = WS_INWT  + 65536;  // 256*128
static constexpr size_t WS_XPWT  = WS_OUTWT + 32768;  // 256*40

// ---------------- partial-stats reduction: grid = 16 (b in 0..1, j in 0..7) ----
__global__ void __launch_bounds__(256)
k_red(const float* __restrict__ part, float* __restrict__ outS, int half){
  __shared__ float red[4];
  int b = blockIdx.x >> 3, j = blockIdx.x & 7;
  float s = 0.f;
  for (int i = b*half + threadIdx.x; i < (b+1)*half; i += 256)
    s += part[(size_t)i*8 + j];
  s += __shfl_xor(s,1); s += __shfl_xor(s,2); s += __shfl_xor(s,4);
  s += __shfl_xor(s,8); s += __shfl_xor(s,16); s += __shfl_xor(s,32);
  if ((threadIdx.x & 63) == 0) red[threadIdx.x>>6] = s;
  __syncthreads();
  if (threadIdx.x == 0) outS[b*8+j] = red[0]+red[1]+red[2]+red[3];
}

// ---------------- transpose weights (spa side only) ----------------
__global__ void __launch_bounds__(256)
k_transpose(const float* __restrict__ pe_w, const float* __restrict__ in_w,
            const float* __restrict__ out_w, const float* __restrict__ xp_w,
            float* __restrict__ peT, float* __restrict__ inT,
            float* __restrict__ outT, float* __restrict__ xpT){
  int i0 = blockIdx.x*256 + threadIdx.x;
  int nt = gridDim.x*256;
  for (int k = i0; k < 128*128; k += nt){ int r = k >> 7, c = k & 127; peT[c*128 + r] = pe_w[k]; }
  for (int k = i0; k < 512*128; k += nt){ int r = k >> 7, c = k & 127; inT[c*512 + r] = in_w[k]; }
  for (int k = i0; k < 128*256; k += nt){ int r = k >> 8, c = k & 255; outT[c*128 + r] = out_w[k]; }
  for (int k = i0; k < 40*256;  k += nt){ int r = k >> 8, c = k & 255; xpT[c*40 + r] = xp_w[k]; }
}

// ---------------- pe 1x1 conv + GN partial stats ----------------
__global__ void __launch_bounds__(256)
k_pe(const float* __restrict__ x, const float* __restrict__ peT,
     const float* __restrict__ pe_b, float* __restrict__ h1pre,
     float* __restrict__ part){
  __shared__ float xs[128][33];
  __shared__ float red1[4][64], red2[4][64];
  int tid = threadIdx.x;
  int m0 = blockIdx.x * 32;
  int b = m0 >> 12, pl = m0 & 4095;
  for (int i = tid; i < 32*128; i += 256){
    int t = i >> 7, c = i & 127;
    xs[c][t] = x[(size_t)(b*128 + c)*4096 + pl + t];
  }
  __syncthreads();
  int o = tid & 127, half = tid >> 7;
  float acc[16];
  #pragma unroll
  for (int t = 0; t < 16; t++) acc[t] = 0.f;
  for (int c = 0; c < 128; c++){
    float wv = peT[c*128 + o];
    const float* xr = &xs[c][half*16];
    #pragma unroll
    for (int t = 0; t < 16; t++) acc[t] += wv * xr[t];
  }
  float bo = pe_b[o];
  float s1 = 0.f, s2 = 0.f;
  for (int t = 0; t < 16; t++){
    float vv = acc[t] + bo;
    s1 += vv; s2 += vv*vv;
    h1pre[(size_t)(m0 + half*16 + t)*128 + o] = vv;
  }
  int g = o >> 5, idx = (o & 31) | (half << 5);
  red1[g][idx] = s1; red2[g][idx] = s2;
  __syncthreads();
  int rg = tid >> 6, ridx = tid & 63;
  for (int s = 32; s >= 1; s >>= 1){
    if (ridx < s){ red1[rg][ridx] += red1[rg][ridx+s]; red2[rg][ridx] += red2[rg][ridx+s]; }
    __syncthreads();
  }
  if (ridx == 0){
    part[(size_t)blockIdx.x*8 + rg*2+0] = red1[rg][0];
    part[(size_t)blockIdx.x*8 + rg*2+1] = red2[rg][0];
  }
}

// ---------------- GN + silu elementwise (pe) ----------------
__global__ void __launch_bounds__(256)
k_gnsilu(const float* __restrict__ pre, const float* __restrict__ stats,
         const float* __restrict__ gw, const float* __restrict__ gb,
         float* __restrict__ outb){
  int idx = blockIdx.x*256 + threadIdx.x;
  int c = idx & 127; int pix = idx >> 7; int b = pix >> 12; int g = c >> 5;
  float s1 = stats[(b*4+g)*2], s2 = stats[(b*4+g)*2+1];
  float m = s1 * (1.f/NG);
  float v = s2 * (1.f/NG) - m*m;
  float xn = (pre[idx] - m) * rsqrtf(v + 1e-5f);
  float val = xn * gw[c] + gb[c];
  outb[idx] = siluf(val);
}

// ---------------- spa in-proj: xz = h1 @ in_w.T ----------------
__global__ void __launch_bounds__(256)
k_xz(const float* __restrict__ h1, const float* __restrict__ inT,
     float* __restrict__ xz){
  __shared__ float xs[128][33];
  int tid = threadIdx.x;
  int m0 = blockIdx.x * 32;
  for (int i = tid; i < 32*128; i += 256){
    int t = i >> 7, c = i & 127;
    xs[c][t] = h1[(size_t)(m0 + t)*128 + c];
  }
  __syncthreads();
  float acc0[32], acc1[32];
  #pragma unroll
  for (int t = 0; t < 32; t++){ acc0[t]=0.f; acc1[t]=0.f; }
  int o = tid;
  for (int c = 0; c < 128; c++){
    float w0 = inT[c*512 + o];
    float w1 = inT[c*512 + o + 256];
    #pragma unroll
    for (int t = 0; t < 32; t++){
      float a = xs[c][t];
      acc0[t] += w0*a; acc1[t] += w1*a;
    }
  }
  for (int t = 0; t < 32; t++){
    xz[(size_t)(m0+t)*512 + o]       = acc0[t];
    xz[(size_t)(m0+t)*512 + o + 256] = acc1[t];
  }
}

// ---------------- causal depthwise conv K=4 + silu; z->silu(z) ----------------
__global__ void __launch_bounds__(256)
k_conv(const float* __restrict__ xz, const float* __restrict__ cw,
       const float* __restrict__ cb, float* __restrict__ xc,
       float* __restrict__ zsil){
  int idx = blockIdx.x*256 + threadIdx.x;
  int d = idx & 255;
  int l = (idx >> 8) & 4095;
  int b = idx >> 20;
  float v = cb[d];
  #pragma unroll
  for (int k = 0; k < 4; k++){
    int ls = l - 3 + k;
    if (ls >= 0) v += xz[(size_t)(b*4096 + ls)*512 + d] * cw[d*4 + k];
  }
  xc[idx] = siluf(v);
  float z = xz[(size_t)(b*4096 + l)*512 + 256 + d];
  zsil[idx] = siluf(z);
}

// ---------------- x-proj (dt,B,C) + delta ----------------
__global__ void __launch_bounds__(256)
k_proj(const float* __restrict__ xc, const float* __restrict__ xpT,
       const float* __restrict__ dtw, const float* __restrict__ dtb,
       float* __restrict__ delta, float* __restrict__ Bm, float* __restrict__ Cm){
  __shared__ float xt[32][260];
  __shared__ float pr[32][40];
  int tid = threadIdx.x;
  int m0 = blockIdx.x * 32;
  for (int i = tid; i < 32*256; i += 256){
    int t = i >> 8, d = i & 255;
    xt[t][d] = xc[(size_t)(m0+t)*256 + d];
  }
  __syncthreads();
  {
    int t = tid >> 3, j0 = tid & 7;
    float a0=0.f,a1=0.f,a2=0.f,a3=0.f,a4=0.f;
    for (int d = 0; d < 256; d++){
      float xv = xt[t][d];
      const float* wp = &xpT[d*40 + j0];
      a0 += xv*wp[0]; a1 += xv*wp[8]; a2 += xv*wp[16]; a3 += xv*wp[24]; a4 += xv*wp[32];
    }
    pr[t][j0] = a0; pr[t][j0+8] = a1; pr[t][j0+16] = a2; pr[t][j0+24] = a3; pr[t][j0+32] = a4;
  }
  __syncthreads();
  {
    int d = tid;
    float w[8];
    #pragma unroll
    for (int r = 0; r < 8; r++) w[r] = dtw[d*8+r];
    float bd = dtb[d];
    for (int t = 0; t < 32; t++){
      float val = bd;
      #pragma unroll
      for (int r = 0; r < 8; r++) val += pr[t][r]*w[r];
      delta[(size_t)(m0+t)*256 + d] = softplusf(val);
    }
  }
  for (int i = tid; i < 512; i += 256){
    int t = i >> 4, n = i & 15;
    Bm[(size_t)(m0+t)*16 + n] = pr[t][8+n];
    Cm[(size_t)(m0+t)*16 + n] = pr[t][24+n];
  }
}

// ---------------- chunked scan phase 1 ----------------
__global__ void __launch_bounds__(256)
k_scan1(const float* __restrict__ delta, const float* __restrict__ xc,
        const float* __restrict__ Bm, const float* __restrict__ Alog,
        float* __restrict__ P, float* __restrict__ Q){
  __shared__ float sd[64][16], sx[64][16], sb[64][16];
  int blk = blockIdx.x;
  int b = blk >> 10;
  int chunk = (blk >> 4) & 63;
  int dblk = blk & 15;
  int tid = threadIdx.x;
  size_t rowbase = (size_t)(b*4096 + chunk*64);
  for (int i = tid; i < 64*16; i += 256){
    int ii = i >> 4, dd = i & 15;
    sd[ii][dd] = delta[(rowbase + ii)*256 + dblk*16 + dd];
    sx[ii][dd] = xc  [(rowbase + ii)*256 + dblk*16 + dd];
    sb[ii][dd] = Bm  [(rowbase + ii)*16 + dd];
  }
  int dl = tid >> 4, n = tid & 15;
  int d = dblk*16 + dl;
  float An = -__expf(Alog[d*16 + n]);
  __syncthreads();
  float Pv = 1.f, Qv = 0.f;
  for (int i = 0; i < 64; i++){
    float dv = sd[i][dl];
    float a = __expf(dv * An);
    Qv = a*Qv + dv * sb[i][n] * sx[i][dl];
    Pv *= a;
  }
  size_t o = (size_t)(b*64+chunk)*4096 + dblk*256 + tid;
  P[o] = Pv; Q[o] = Qv;
}

// ---------------- chunked scan phase 2 ----------------
__global__ void __launch_bounds__(256)
k_scan2(const float* __restrict__ P, const float* __restrict__ Q,
        float* __restrict__ hs){
  int gid = blockIdx.x*256 + threadIdx.x;
  int b = gid >> 12, dn = gid & 4095;
  float h = 0.f;
  for (int ch = 0; ch < 64; ch++){
    size_t idx = (size_t)(b*64 + ch)*4096 + dn;
    hs[idx] = h;
    h = P[idx]*h + Q[idx];
  }
}

// ---------------- chunked scan phase 3 ----------------
__global__ void __launch_bounds__(256)
k_scan3(const float* __restrict__ delta, const float* __restrict__ xc,
        const float* __restrict__ Bm, const float* __restrict__ Cm,
        const float* __restrict__ zsil, const float* __restrict__ Alog,
        const float* __restrict__ Dv, const float* __restrict__ hs,
        float* __restrict__ y){
  __shared__ float sd[64][16], sx[64][16], sb[64][16], sc[64][16], sz[64][16], yt[64][16];
  int blk = blockIdx.x;
  int b = blk >> 10;
  int chunk = (blk >> 4) & 63;
  int dblk = blk & 15;
  int tid = threadIdx.x;
  size_t rowbase = (size_t)(b*4096 + chunk*64);
  for (int i = tid; i < 64*16; i += 256){
    int ii = i >> 4, dd = i & 15;
    sd[ii][dd] = delta[(rowbase + ii)*256 + dblk*16 + dd];
    sx[ii][dd] = xc  [(rowbase + ii)*256 + dblk*16 + dd];
    sz[ii][dd] = zsil[(rowbase + ii)*256 + dblk*16 + dd];
    sb[ii][dd] = Bm  [(rowbase + ii)*16 + dd];
    sc[ii][dd] = Cm  [(rowbase + ii)*16 + dd];
  }
  int dl = tid >> 4, n = tid & 15;
  int d = dblk*16 + dl;
  float An = -__expf(Alog[d*16 + n]);
  float h = hs[(size_t)(b*64+chunk)*4096 + dblk*256 + tid];
  float Dd = Dv[d];
  __syncthreads();
  for (int i = 0; i < 64; i++){
    float dv = sd[i][dl], xv = sx[i][dl];
    float a = __expf(dv * An);
    h = a*h + dv * sb[i][n] * xv;
    float ctr = h * sc[i][n];
    ctr += __shfl_xor(ctr, 1);
    ctr += __shfl_xor(ctr, 2);
    ctr += __shfl_xor(ctr, 4);
    ctr += __shfl_xor(ctr, 8);
    if (n == 0) yt[i][dl] = (ctr + Dd*xv) * sz[i][dl];
  }
  __syncthreads();
  for (int i = tid; i < 1024; i += 256){
    int ii = i >> 4, dd = i & 15;
    y[(rowbase + ii)*256 + dblk*16 + dd] = yt[ii][dd];
  }
}

// ---------------- spa out-proj + GN partial stats ----------------
__global__ void __launch_bounds__(256)
k_outproj(const float* __restrict__ y, const float* __restrict__ outT,
          float* __restrict__ yproj, float* __restrict__ part){
  __shared__ float ytile[256][33];
  __shared__ float red1[4][64], red2[4][64];
  int tid = threadIdx.x;
  int m0 = blockIdx.x * 32;
  for (int i = tid; i < 32*256; i += 256){
    int t = i >> 8, d = i & 255;
    ytile[d][t] = y[(size_t)(m0+t)*256 + d];
  }
  __syncthreads();
  int o = tid & 127, half = tid >> 7;
  float acc[16];
  #pragma unroll
  for (int t = 0; t < 16; t++) acc[t] = 0.f;
  for (int d = 0; d < 256; d++){
    float wv = outT[d*128 + o];
    const float* yr = &ytile[d][half*16];
    #pragma unroll
    for (int t = 0; t < 16; t++) acc[t] += wv * yr[t];
  }
  float s1 = 0.f, s2 = 0.f;
  for (int t = 0; t < 16; t++){
    float vv = acc[t];
    s1 += vv; s2 += vv*vv;
    yproj[(size_t)(m0 + half*16 + t)*128 + o] = vv;
  }
  int g = o >> 5, idx = (o & 31) | (half << 5);
  red1[g][idx] = s1; red2[g][idx] = s2;
  __syncthreads();
  int rg = tid >> 6, ridx = tid & 63;
  for (int s = 32; s >= 1; s >>= 1){
    if (ridx < s){ red1[rg][ridx] += red1[rg][ridx+s]; red2[rg][ridx] += red2[rg][ridx+s]; }
    __syncthreads();
  }
  if (ridx == 0){
    part[(size_t)blockIdx.x*8 + rg*2+0] = red1[rg][0];
    part[(size_t)blockIdx.x*8 + rg*2+1] = red2[rg][0];
  }
}

// ---------------- spe A: in-proj + conv + silu (reg weights, lane=d) ----------
// grid 512 x 256; wave handles 4 pixels. tok = pix*4 + l.
__global__ void __launch_bounds__(256)
k_spe_a(const float* __restrict__ h1, const float* __restrict__ in_w,
        const float* __restrict__ conv_w, const float* __restrict__ conv_b,
        float* __restrict__ xc2, float* __restrict__ xc2T,
        float* __restrict__ zsil2){
  __shared__ float s_in[4][128];
  int tid = threadIdx.x;
  int w = tid >> 6, lane = tid & 63;
  // per-lane weights: in_w rows lane (x) and 64+lane (z), 32 floats each
  float wx[32], wz[32];
  {
    const float4* rx = (const float4*)(in_w + (size_t)lane*32);
    const float4* rz = (const float4*)(in_w + (size_t)(64+lane)*32);
    #pragma unroll
    for (int k = 0; k < 8; k++){
      float4 a = rx[k]; wx[k*4]=a.x; wx[k*4+1]=a.y; wx[k*4+2]=a.z; wx[k*4+3]=a.w;
      float4 b = rz[k]; wz[k*4]=b.x; wz[k*4+1]=b.y; wz[k*4+2]=b.z; wz[k*4+3]=b.w;
    }
  }
  float4 cwv = ((const float4*)conv_w)[lane];
  float cbv = conv_b[lane];
  for (int i = 0; i < 4; i++){
    int pix = blockIdx.x*16 + w*4 + i;
    // stage h1 row (wave-private; DS ops are in-order per wave)
    float2 hv = ((const float2*)(h1 + (size_t)pix*128))[lane];
    s_in[w][2*lane] = hv.x; s_in[w][2*lane+1] = hv.y;
    float xpr[4], zs[4];
    #pragma unroll
    for (int l = 0; l < 4; l++){
      const float4* sv = (const float4*)&s_in[w][l*32];
      float ax = 0.f, az = 0.f;
      #pragma unroll
      for (int c4 = 0; c4 < 8; c4++){
        float4 v = sv[c4];
        ax += v.x*wx[c4*4] + v.y*wx[c4*4+1] + v.z*wx[c4*4+2] + v.w*wx[c4*4+3];
        az += v.x*wz[c4*4] + v.y*wz[c4*4+1] + v.z*wz[c4*4+2] + v.w*wz[c4*4+3];
      }
      xpr[l] = ax; zs[l] = siluf(az);
    }
    #pragma unroll
    for (int l = 0; l < 4; l++){
      float v = cbv;
      if (l >= 3) v += xpr[l-3]*cwv.x;
      if (l >= 2) v += xpr[l-2]*cwv.y;
      if (l >= 1) v += xpr[l-1]*cwv.z;
      v += xpr[l]*cwv.w;
      float sx = siluf(v);
      int tok = pix*4 + l;
      xc2 [(size_t)tok*64 + lane] = sx;
      xc2T[(size_t)lane*32768 + tok] = sx;
      zsil2[(size_t)tok*64 + lane] = zs[l];
    }
  }
}

// ---------------- spe B: x-proj GEMM, thread = token --------------------------
// grid 128 x 256. xpw is spe_xproj_w [34][64] row-major (weights wave-uniform).
__global__ void __launch_bounds__(256)
k_spe_b(const float* __restrict__ xc2T, const float* __restrict__ xpw,
        float* __restrict__ proj){
  int tok = blockIdx.x*256 + threadIdx.x;
  float xcv[64];
  #pragma unroll 64
  for (int dd = 0; dd < 64; dd++) xcv[dd] = xc2T[(size_t)dd*32768 + tok];
  float* pr = proj + (size_t)tok*36;
  #pragma unroll 2
  for (int j = 0; j < 34; j++){
    const float4* wr = (const float4*)(xpw + j*64);
    float a = 0.f;
    #pragma unroll
    for (int k = 0; k < 16; k++){
      float4 wv = wr[k];
      a += xcv[k*4]*wv.x + xcv[k*4+1]*wv.y + xcv[k*4+2]*wv.z + xcv[k*4+3]*wv.w;
    }
    pr[j] = a;
  }
}

// ---------------- spe C: delta + scan + gate (lane=d, 4 pixels/wave) ----------
__global__ void __launch_bounds__(256)
k_spe_c(const float* __restrict__ xc2, const float* __restrict__ zsil2,
        const float* __restrict__ proj, const float* __restrict__ dt_w,
        const float* __restrict__ dt_b, const float* __restrict__ Alog,
        const float* __restrict__ Dvec, float* __restrict__ yg){
  int tid = threadIdx.x;
  int w = tid >> 6, lane = tid & 63;
  float2 dtwv = ((const float2*)dt_w)[lane];
  float dbv = dt_b[lane], Dd = Dvec[lane];
  float An[16];
  {
    const float4* ar = (const float4*)(Alog + (size_t)lane*16);
    #pragma unroll
    for (int k = 0; k < 4; k++){
      float4 a = ar[k];
      An[k*4]   = -__expf(a.x); An[k*4+1] = -__expf(a.y);
      An[k*4+2] = -__expf(a.z); An[k*4+3] = -__expf(a.w);
    }
  }
  for (int i = 0; i < 4; i++){
    int pix = blockIdx.x*16 + w*4 + i;
    float h[16];
    #pragma unroll
    for (int n = 0; n < 16; n++) h[n] = 0.f;
    #pragma unroll
    for (int l = 0; l < 4; l++){
      int tok = pix*4 + l;
      float pj[36];
      {
        const float4* pr = (const float4*)(proj + (size_t)tok*36);
        #pragma unroll
        for (int k = 0; k < 9; k++){
          float4 v = pr[k];
          pj[k*4]=v.x; pj[k*4+1]=v.y; pj[k*4+2]=v.z; pj[k*4+3]=v.w;
        }
      }
      float xv = xc2[(size_t)tok*64 + lane];
      float zv = zsil2[(size_t)tok*64 + lane];
      float dt = softplusf(dbv + pj[0]*dtwv.x + pj[1]*dtwv.y);
      float ys = 0.f;
      #pragma unroll
      for (int n = 0; n < 16; n++){
        float a = __expf(dt * An[n]);
        h[n] = a*h[n] + dt * pj[2+n] * xv;
        ys += h[n] * pj[18+n];
      }
      yg[(size_t)tok*64 + lane] = (ys + Dd*xv) * zv;
    }
  }
}

// ---------------- spe D: out-proj GEMM + GN partial stats ---------------------
// grid 512 x 256; block = 64 tokens; wave = 16 tokens (32 c2 x 2 slots x 8 i).
__global__ void __launch_bounds__(256)
k_spe_d(const float* __restrict__ yg, const float* __restrict__ out_w,
        float* __restrict__ y2, float* __restrict__ part){
  __shared__ float ldsWT[64*32];   // [dd][c2] conflict-free
  __shared__ float bst[8];
  int tid = threadIdx.x;
  for (int i = tid; i < 2048; i += 256){
    int c2 = i >> 6, dd = i & 63;
    ldsWT[dd*32 + c2] = out_w[i];
  }
  if (tid < 8) bst[tid] = 0.f;
  __syncthreads();
  int w = tid >> 6, lane = tid & 63;
  int c2 = lane & 31, slot = lane >> 5;
  int tokbase = blockIdx.x*64 + w*16 + slot;
  float acc[8];
  #pragma unroll
  for (int i = 0; i < 8; i++) acc[i] = 0.f;
  for (int dd4 = 0; dd4 < 16; dd4++){
    float w0 = ldsWT[(dd4*4+0)*32 + c2];
    float w1 = ldsWT[(dd4*4+1)*32 + c2];
    float w2 = ldsWT[(dd4*4+2)*32 + c2];
    float w3 = ldsWT[(dd4*4+3)*32 + c2];
    #pragma unroll
    for (int i = 0; i < 8; i++){
      int tok = tokbase + 2*i;
      float4 yv = ((const float4*)(yg + (size_t)tok*64))[dd4];
      acc[i] += yv.x*w0 + yv.y*w1 + yv.z*w2 + yv.w*w3;
    }
  }
  #pragma unroll
  for (int i = 0; i < 8; i++){
    int tok = tokbase + 2*i;
    int pix = tok >> 2, l = tok & 3;
    y2[(size_t)pix*128 + l*32 + c2] = acc[i];
    float s1 = acc[i], s2 = acc[i]*acc[i];
    s1 += __shfl_xor(s1,1);  s2 += __shfl_xor(s2,1);
    s1 += __shfl_xor(s1,2);  s2 += __shfl_xor(s2,2);
    s1 += __shfl_xor(s1,4);  s2 += __shfl_xor(s2,4);
    s1 += __shfl_xor(s1,8);  s2 += __shfl_xor(s2,8);
    s1 += __shfl_xor(s1,16); s2 += __shfl_xor(s2,16);
    if (c2 == 0){
      atomicAdd(&bst[l*2+0], s1);
      atomicAdd(&bst[l*2+1], s2);
    }
  }
  __syncthreads();
  if (tid < 8) part[(size_t)blockIdx.x*8 + tid] = bst[tid];
}

// ---------------- fuse: GN(spa)+GN(spe)+h1 -> feat, logits ----------------
__global__ void __launch_bounds__(256)
k_fuse(const float* __restrict__ h1, const float* __restrict__ yproj,
       const float* __restrict__ y2, const float* __restrict__ stats,
       const float* __restrict__ spa_g, const float* __restrict__ spa_b,
       const float* __restrict__ spe_g, const float* __restrict__ spe_b,
       const float* __restrict__ fuse_w, const float* __restrict__ cls_w,
       const float* __restrict__ cls_b, float* __restrict__ feat,
       float* __restrict__ logits){
  __shared__ float ft[2][128];
  int tid = threadIdx.x;
  int pixl = tid >> 7, c = tid & 127;
  int pix = blockIdx.x*2 + pixl;
  int b = pix >> 12, g = c >> 5;
  float m1 = stats[16 + (b*4+g)*2]   * (1.f/NG);
  float v1 = stats[16 + (b*4+g)*2+1] * (1.f/NG) - m1*m1;
  float m2 = stats[32 + (b*4+g)*2]   * (1.f/NG);
  float v2 = stats[32 + (b*4+g)*2+1] * (1.f/NG) - m2*m2;
  float h = h1[(size_t)pix*128 + c];
  float sa = siluf((yproj[(size_t)pix*128+c] - m1)*rsqrtf(v1+1e-5f)*spa_g[c] + spa_b[c]) + h;
  float sp = h + siluf((y2[(size_t)pix*128+c] - m2)*rsqrtf(v2+1e-5f)*spe_g[c] + spe_b[c]);
  float e0 = __expf(fuse_w[0]), e1 = __expf(fuse_w[1]);
  float w0 = e0/(e0+e1), w1 = e1/(e0+e1);
  float f = sa*w0 + sp*w1 + h;
  feat[(size_t)pix*128+c] = f;
  ft[pixl][c] = f;
  __syncthreads();
  if (tid < 20){
    int pl = (tid >= 10) ? 1 : 0;
    int o = tid - pl*10;
    float acc = cls_b[o];
    for (int cc = 0; cc < 128; cc++) acc += ft[pl][cc]*cls_w[o*128+cc];
    logits[(size_t)(blockIdx.x*2 + pl)*16 + o] = acc;
  }
}

// ---------------- depthwise 3x3 on feat + GN partial stats ----------------
__global__ void __launch_bounds__(256)
k_dw(const float* __restrict__ feat, const float* __restrict__ dww,
     float* __restrict__ epre, float* __restrict__ part){
  __shared__ float red1[4][64], red2[4][64];
  int tid = threadIdx.x;
  int pixl = tid >> 7, c = tid & 127;
  int pix = blockIdx.x*2 + pixl;
  int b = pix >> 12, p = pix & 4095, yy = p >> 6, xx = p & 63;
  float acc = 0.f;
  for (int dy = -1; dy <= 1; dy++){
    int ny = yy + dy; if (ny < 0 || ny > 63) continue;
    for (int dx = -1; dx <= 1; dx++){
      int nx = xx + dx; if (nx < 0 || nx > 63) continue;
      acc += feat[(size_t)((b<<12)|(ny<<6)|nx)*128 + c] * dww[c*9 + (dy+1)*3 + (dx+1)];
    }
  }
  epre[(size_t)pix*128 + c] = acc;
  int g = c >> 5;
  int idx = (c & 31) | (pixl << 5);
  red1[g][idx] = acc; red2[g][idx] = acc*acc;
  __syncthreads();
  int rg = tid >> 6, ridx = tid & 63;
  for (int s = 32; s >= 1; s >>= 1){
    if (ridx < s){ red1[rg][ridx] += red1[rg][ridx+s]; red2[rg][ridx] += red2[rg][ridx+s]; }
    __syncthreads();
  }
  if (ridx == 0){
    part[(size_t)blockIdx.x*8 + rg*2+0] = red1[rg][0];
    part[(size_t)blockIdx.x*8 + rg*2+1] = red2[rg][0];
  }
}

// ---------------- edge + local avg + final output ----------------
__global__ void __launch_bounds__(256)
k_final(const float* __restrict__ epre, const float* __restrict__ logits,
        const float* __restrict__ stats, const float* __restrict__ rg_g,
        const float* __restrict__ rg_b, const float* __restrict__ pw_w,
        const float* __restrict__ pw_b, const float* __restrict__ alpha,
        float* __restrict__ outp){
  __shared__ float part[4];
  __shared__ float edge_s[2];
  int tid = threadIdx.x;
  int pixl = tid >> 7, c = tid & 127;
  int pix = blockIdx.x*2 + pixl;
  int b = pix >> 12, p = pix & 4095, yy = p >> 6, xx = p & 63;
  int g = c >> 5;
  float m = stats[48 + (b*4+g)*2]   * (1.f/NG);
  float v = stats[48 + (b*4+g)*2+1] * (1.f/NG) - m*m;
  float e = epre[(size_t)pix*128+c];
  float en = siluf((e-m)*rsqrtf(v+1e-5f)*rg_g[c] + rg_b[c]);
  float pv = en * pw_w[c];
  pv += __shfl_xor(pv,1);  pv += __shfl_xor(pv,2);  pv += __shfl_xor(pv,4);
  pv += __shfl_xor(pv,8);  pv += __shfl_xor(pv,16); pv += __shfl_xor(pv,32);
  if ((tid & 63) == 0) part[tid>>6] = pv;
  __syncthreads();
  if (tid < 2) edge_s[tid] = sigm(part[tid*2] + part[tid*2+1] + pw_b[0]);
  __syncthreads();
  if (c < 10){
    float ed = edge_s[pixl];
    int o = c;
    float lg = logits[(size_t)pix*16 + o];
    float loc = 0.f;
    for (int dy = -1; dy <= 1; dy++){
      int ny = yy+dy; if (ny < 0 || ny > 63) continue;
      for (int dx = -1; dx <= 1; dx++){
        int nx = xx+dx; if (nx < 0 || nx > 63) continue;
        loc += logits[(size_t)((b<<12)|(ny<<6)|nx)*16 + o];
      }
    }
    loc *= (1.f/9.f);
    outp[(size_t)((b*10+o)<<12) + p] = lg + alpha[0]*(1.f-ed)*(loc - lg);
  }
}

extern "C" void kernel_launch(void* const* d_in, const int* in_sizes, int n_in,
                              void* d_out, int out_size, void* d_ws, size_t ws_size,
                              hipStream_t stream){
  const float* x          = (const float*)d_in[0];
  const float* pe_w       = (const float*)d_in[1];
  const float* pe_b       = (const float*)d_in[2];
  const float* pe_gn_g    = (const float*)d_in[3];
  const float* pe_gn_b    = (const float*)d_in[4];
  const float* spa_in_w   = (const float*)d_in[5];
  const float* spa_conv_w = (const float*)d_in[6];
  const float* spa_conv_b = (const float*)d_in[7];
  const float* spa_xproj_w= (const float*)d_in[8];
  const float* spa_dt_w   = (const float*)d_in[9];
  const float* spa_dt_b   = (const float*)d_in[10];
  const float* spa_Alog   = (const float*)d_in[11];
  const float* spa_D      = (const float*)d_in[12];
  const float* spa_out_w  = (const float*)d_in[13];
  const float* spa_gn_g   = (const float*)d_in[14];
  const float* spa_gn_b   = (const float*)d_in[15];
  const float* spe_in_w   = (const float*)d_in[16];
  const float* spe_conv_w = (const float*)d_in[17];
  const float* spe_conv_b = (const float*)d_in[18];
  const float* spe_xproj_w= (const float*)d_in[19];
  const float* spe_dt_w   = (const float*)d_in[20];
  const float* spe_dt_b   = (const float*)d_in[21];
  const float* spe_Alog   = (const float*)d_in[22];
  const float* spe_D      = (const float*)d_in[23];
  const float* spe_out_w  = (const float*)d_in[24];
  const float* spe_gn_g   = (const float*)d_in[25];
  const float* spe_gn_b   = (const float*)d_in[26];
  const float* fuse_w     = (const float*)d_in[27];
  const float* cls_w      = (const float*)d_in[28];
  const float* cls_b      = (const float*)d_in[29];
  const float* ref_dw_w   = (const float*)d_in[30];
  const float* ref_gn_g   = (const float*)d_in[31];
  const float* ref_gn_b   = (const float*)d_in[32];
  const float* ref_pw_w   = (const float*)d_in[33];
  const float* ref_pw_b   = (const float*)d_in[34];
  const float* alpha      = (const float*)d_in[35];
  float* ws  = (float*)d_ws;
  float* out = (float*)d_out;

  // partials buffers reuse dead scratch:
  float* partPE  = ws + WS_Y;
  float* partSPA = ws + WS_HS;
  float* partSPE = ws + WS_Q;
  float* partDW  = ws + WS_P;
  // spe scratch reusing dead spa regions:
  float* xc2   = ws + WS_XC;     // [32768][64]
  float* xc2T  = ws + WS_ZSIL;   // [64][32768]
  float* zsil2 = ws + WS_DELTA;  // [32768][64]
  float* proj  = ws + WS_BM;     // [32768][36]
  float* yg    = ws + WS_Y;      // [32768][64]

  k_transpose<<<64,256,0,stream>>>(pe_w, spa_in_w, spa_out_w, spa_xproj_w,
      ws+WS_PEWT, ws+WS_INWT, ws+WS_OUTWT, ws+WS_XPWT);
  k_pe<<<256,256,0,stream>>>(x, ws+WS_PEWT, pe_b, ws+WS_H1PRE, partPE);
  k_red<<<16,256,0,stream>>>(partPE, ws+WS_STATS+0, 128);
  k_gnsilu<<<4096,256,0,stream>>>(ws+WS_H1PRE, ws+WS_STATS, pe_gn_g, pe_gn_b, ws+WS_H1);
  k_xz<<<256,256,0,stream>>>(ws+WS_H1, ws+WS_INWT, ws+WS_XZ);
  k_conv<<<8192,256,0,stream>>>(ws+WS_XZ, spa_conv_w, spa_conv_b, ws+WS_XC, ws+WS_ZSIL);
  k_proj<<<256,256,0,stream>>>(ws+WS_XC, ws+WS_XPWT, spa_dt_w, spa_dt_b,
      ws+WS_DELTA, ws+WS_BM, ws+WS_CM);
  k_scan1<<<2048,256,0,stream>>>(ws+WS_DELTA, ws+WS_XC, ws+WS_BM, spa_Alog, ws+WS_P, ws+WS_Q);
  k_scan2<<<32,256,0,stream>>>(ws+WS_P, ws+WS_Q, ws+WS_HS);
  k_scan3<<<2048,256,0,stream>>>(ws+WS_DELTA, ws+WS_XC, ws+WS_BM, ws+WS_CM,
      ws+WS_ZSIL, spa_Alog, spa_D, ws+WS_HS, ws+WS_Y);
  k_outproj<<<256,256,0,stream>>>(ws+WS_Y, ws+WS_OUTWT, ws+WS_H1PRE, partSPA);
  k_red<<<16,256,0,stream>>>(partSPA, ws+WS_STATS+16, 128);
  k_spe_a<<<512,256,0,stream>>>(ws+WS_H1, spe_in_w, spe_conv_w, spe_conv_b,
      xc2, xc2T, zsil2);
  k_spe_b<<<128,256,0,stream>>>(xc2T, spe_xproj_w, proj);
  k_spe_c<<<512,256,0,stream>>>(xc2, zsil2, proj, spe_dt_w, spe_dt_b,
      spe_Alog, spe_D, yg);
  k_spe_d<<<512,256,0,stream>>>(yg, spe_out_w, ws+WS_Y2, partSPE);
  k_red<<<16,256,0,stream>>>(partSPE, ws+WS_STATS+32, 256);
  k_fuse<<<4096,256,0,stream>>>(ws+WS_H1, ws+WS_H1PRE, ws+WS_Y2, ws+WS_STATS,
      spa_gn_g, spa_gn_b, spe_gn_g, spe_gn_b, fuse_w, cls_w, cls_b,
      ws+WS_FEAT, ws+WS_LOG);
  k_dw<<<4096,256,0,stream>>>(ws+WS_FEAT, ref_dw_w, ws+WS_Y, partDW);
  k_red<<<16,256,0,stream>>>(partDW, ws+WS_STATS+48, 2048);
  k_final<<<4096,256,0,stream>>>(ws+WS_Y, ws+WS_LOG, ws+WS_STATS,
      ref_gn_g, ref_gn_b, ref_pw_w, ref_pw_b, alpha, out);
  (void)in_sizes; (void)n_in; (void)out_size; (void)ws_size;
}

// Round 4
// 407.881 us; speedup vs baseline: 2.3561x; 1.1313x over previous
//
#include <hip/hip_runtime.h>
#include <math.h>

#define DEV __device__ __forceinline__

DEV float sigm(float x){ return 1.f/(1.f+__expf(-x)); }
DEV float siluf(float x){ return x * sigm(x); }
DEV float softplusf(float x){ return x > 20.f ? x : log1pf(__expf(x)); }

static constexpr float NG = 131072.0f;   // group-norm element count per (b,g): 32*64*64

// ---- workspace layout (offsets in floats) ----
static constexpr size_t WS_H1    = 0;          // B*HW*128
static constexpr size_t WS_H1PRE = 1048576;    // B*HW*128 (reused as yproj)
static constexpr size_t WS_XC    = 2097152;    // B*HW*256 (spa xc; later spe xc2[tok][64])
static constexpr size_t WS_ZSIL  = 4194304;    // B*HW*256 (spa zsil; later spe xc2T[64][tok])
static constexpr size_t WS_XZ    = 6291456;    // B*HW*512  (xz; later delta; later spe zsil2)
static constexpr size_t WS_DELTA = 6291456;    // B*HW*256
static constexpr size_t WS_BM    = 8388608;    // B*HW*16 (later spe proj[tok][36])
static constexpr size_t WS_CM    = 8519680;    // B*HW*16
static constexpr size_t WS_LOG   = 8650752;    // B*HW*16 (logits, stride 16, 10 used)
static constexpr size_t WS_Y     = 10485760;   // B*HW*256 (y; pe partials; spe yg; later e_pre)
static constexpr size_t WS_P     = 12582912;   // B*64*256*16 (after scan3: dw partials)
static constexpr size_t WS_Q     = 13107200;   // (after scan3: spe partials)
static constexpr size_t WS_HS    = 13631488;   // (after scan3: outproj partials)
static constexpr size_t WS_Y2    = 14155776;   // B*HW*128
static constexpr size_t WS_FEAT  = 15204352;   // B*HW*128
static constexpr size_t WS_STATS = 16252928;   // 64 floats: pe@0 spa@16 spe@32 ref@48
static constexpr size_t WS_PEWT  = 16253056;   // 128*128
static constexpr size_t WS_INWT  = WS_PEWT  + 16384;  // 128*512
static constexpr size_t WS_OUTWT = WS_INWT  + 65536;  // 256*128
static constexpr size_t WS_XPWT  = WS_OUTWT + 32768;  // 256*40

// ---------------- partial-stats reduction: grid = 16 (b in 0..1, j in 0..7) ----
__global__ void __launch_bounds__(256)
k_red(const float* __restrict__ part, float* __restrict__ outS, int half){
  __shared__ float red[4];
  int b = blockIdx.x >> 3, j = blockIdx.x & 7;
  float s = 0.f;
  for (int i = b*half + threadIdx.x; i < (b+1)*half; i += 256)
    s += part[(size_t)i*8 + j];
  s += __shfl_xor(s,1); s += __shfl_xor(s,2); s += __shfl_xor(s,4);
  s += __shfl_xor(s,8); s += __shfl_xor(s,16); s += __shfl_xor(s,32);
  if ((threadIdx.x & 63) == 0) red[threadIdx.x>>6] = s;
  __syncthreads();
  if (threadIdx.x == 0) outS[b*8+j] = red[0]+red[1]+red[2]+red[3];
}

// ---------------- transpose weights (spa side only) ----------------
__global__ void __launch_bounds__(256)
k_transpose(const float* __restrict__ pe_w, const float* __restrict__ in_w,
            const float* __restrict__ out_w, const float* __restrict__ xp_w,
            float* __restrict__ peT, float* __restrict__ inT,
            float* __restrict__ outT, float* __restrict__ xpT){
  int i0 = blockIdx.x*256 + threadIdx.x;
  int nt = gridDim.x*256;
  for (int k = i0; k < 128*128; k += nt){ int r = k >> 7, c = k & 127; peT[c*128 + r] = pe_w[k]; }
  for (int k = i0; k < 512*128; k += nt){ int r = k >> 7, c = k & 127; inT[c*512 + r] = in_w[k]; }
  for (int k = i0; k < 128*256; k += nt){ int r = k >> 8, c = k & 255; outT[c*128 + r] = out_w[k]; }
  for (int k = i0; k < 40*256;  k += nt){ int r = k >> 8, c = k & 255; xpT[c*40 + r] = xp_w[k]; }
}

// ---------------- pe 1x1 conv (tiled GEMM 32x64) + GN partial stats ----------
// grid (256, 2); m0 = bx*32 pixels, n0 = by*64 outputs. A from NCHW x.
__global__ void __launch_bounds__(256)
k_pe(const float* __restrict__ x, const float* __restrict__ peT,
     const float* __restrict__ pe_b, float* __restrict__ h1pre,
     float* __restrict__ part){
  __shared__ float As[16][36];
  __shared__ float Bs[16][64];
  __shared__ float red1[2][4], red2[2][4];
  int tid = threadIdx.x;
  int bx = blockIdx.x, by = blockIdx.y;
  int m0 = bx*32, n0 = by*64;
  int b = m0 >> 12, pl0 = m0 & 4095;
  int tx = tid & 15, ty = tid >> 4;
  float acc[2][4];
  #pragma unroll
  for (int i = 0; i < 2; i++)
    #pragma unroll
    for (int j = 0; j < 4; j++) acc[i][j] = 0.f;
  for (int k0 = 0; k0 < 128; k0 += 16){
    if (tid < 128){
      int k = tid >> 3, mm = (tid & 7)*4;
      float4 a = *(const float4*)(x + ((size_t)b*128 + k0+k)*4096 + pl0 + mm);
      *(float4*)&As[k][mm] = a;
    }
    {
      int k = tid >> 4, n = (tid & 15)*4;
      *(float4*)&Bs[k][n] = *(const float4*)(peT + (size_t)(k0+k)*128 + n0+n);
    }
    __syncthreads();
    #pragma unroll
    for (int k = 0; k < 16; k++){
      float2 av = *(const float2*)&As[k][ty*2];
      float4 bv = *(const float4*)&Bs[k][tx*4];
      acc[0][0] += av.x*bv.x; acc[0][1] += av.x*bv.y; acc[0][2] += av.x*bv.z; acc[0][3] += av.x*bv.w;
      acc[1][0] += av.y*bv.x; acc[1][1] += av.y*bv.y; acc[1][2] += av.y*bv.z; acc[1][3] += av.y*bv.w;
    }
    __syncthreads();
  }
  float4 bias = *(const float4*)(pe_b + n0 + tx*4);
  float s1 = 0.f, s2 = 0.f;
  #pragma unroll
  for (int i = 0; i < 2; i++){
    float4 st;
    st.x = acc[i][0]+bias.x; st.y = acc[i][1]+bias.y;
    st.z = acc[i][2]+bias.z; st.w = acc[i][3]+bias.w;
    s1 += st.x+st.y+st.z+st.w;
    s2 += st.x*st.x + st.y*st.y + st.z*st.z + st.w*st.w;
    *(float4*)(h1pre + (size_t)(m0 + ty*2 + i)*128 + n0 + tx*4) = st;
  }
  // reduce: xor over tx-within-octet {1,2,4} then ty {16,32}
  s1 += __shfl_xor(s1,1);  s2 += __shfl_xor(s2,1);
  s1 += __shfl_xor(s1,2);  s2 += __shfl_xor(s2,2);
  s1 += __shfl_xor(s1,4);  s2 += __shfl_xor(s2,4);
  s1 += __shfl_xor(s1,16); s2 += __shfl_xor(s2,16);
  s1 += __shfl_xor(s1,32); s2 += __shfl_xor(s2,32);
  int lane = tid & 63, w = tid >> 6;
  if ((lane & 55) == 0){
    int gl = (lane >> 3) & 1;
    red1[gl][w] = s1; red2[gl][w] = s2;
  }
  __syncthreads();
  if (tid < 8){
    int gg = tid >> 1, which = tid & 1;
    int gl = gg - by*2;
    float v = 0.f;
    if (gl == 0 || gl == 1){
      v = which ? (red2[gl][0]+red2[gl][1]+red2[gl][2]+red2[gl][3])
                : (red1[gl][0]+red1[gl][1]+red1[gl][2]+red1[gl][3]);
    }
    int pblk = b*256 + (bx & 127) + by*128;
    part[(size_t)pblk*8 + tid] = v;
  }
}

// ---------------- GN + silu elementwise (pe) ----------------
__global__ void __launch_bounds__(256)
k_gnsilu(const float* __restrict__ pre, const float* __restrict__ stats,
         const float* __restrict__ gw, const float* __restrict__ gb,
         float* __restrict__ outb){
  int idx = blockIdx.x*256 + threadIdx.x;
  int c = idx & 127; int pix = idx >> 7; int b = pix >> 12; int g = c >> 5;
  float s1 = stats[(b*4+g)*2], s2 = stats[(b*4+g)*2+1];
  float m = s1 * (1.f/NG);
  float v = s2 * (1.f/NG) - m*m;
  float xn = (pre[idx] - m) * rsqrtf(v + 1e-5f);
  float val = xn * gw[c] + gb[c];
  outb[idx] = siluf(val);
}

// ---------------- spa in-proj: tiled GEMM 64x64, grid (128,8) ----------------
__global__ void __launch_bounds__(256)
k_xz(const float* __restrict__ h1, const float* __restrict__ inT,
     float* __restrict__ xz){
  __shared__ float As[16][68];
  __shared__ float Bs[16][64];
  int tid = threadIdx.x;
  int m0 = blockIdx.x*64, n0 = blockIdx.y*64;
  int tx = tid & 15, ty = tid >> 4;
  float acc[4][4];
  #pragma unroll
  for (int i = 0; i < 4; i++)
    #pragma unroll
    for (int j = 0; j < 4; j++) acc[i][j] = 0.f;
  for (int k0 = 0; k0 < 128; k0 += 16){
    {
      int m = tid >> 2, kk = (tid & 3)*4;
      float4 a = *(const float4*)(h1 + (size_t)(m0+m)*128 + k0+kk);
      As[kk+0][m] = a.x; As[kk+1][m] = a.y; As[kk+2][m] = a.z; As[kk+3][m] = a.w;
    }
    {
      int k = tid >> 4, n = (tid & 15)*4;
      *(float4*)&Bs[k][n] = *(const float4*)(inT + (size_t)(k0+k)*512 + n0+n);
    }
    __syncthreads();
    #pragma unroll
    for (int k = 0; k < 16; k++){
      float4 av = *(const float4*)&As[k][ty*4];
      float4 bv = *(const float4*)&Bs[k][tx*4];
      acc[0][0] += av.x*bv.x; acc[0][1] += av.x*bv.y; acc[0][2] += av.x*bv.z; acc[0][3] += av.x*bv.w;
      acc[1][0] += av.y*bv.x; acc[1][1] += av.y*bv.y; acc[1][2] += av.y*bv.z; acc[1][3] += av.y*bv.w;
      acc[2][0] += av.z*bv.x; acc[2][1] += av.z*bv.y; acc[2][2] += av.z*bv.z; acc[2][3] += av.z*bv.w;
      acc[3][0] += av.w*bv.x; acc[3][1] += av.w*bv.y; acc[3][2] += av.w*bv.z; acc[3][3] += av.w*bv.w;
    }
    __syncthreads();
  }
  #pragma unroll
  for (int i = 0; i < 4; i++){
    float4 st; st.x = acc[i][0]; st.y = acc[i][1]; st.z = acc[i][2]; st.w = acc[i][3];
    *(float4*)(xz + (size_t)(m0 + ty*4 + i)*512 + n0 + tx*4) = st;
  }
}

// ---------------- causal depthwise conv K=4 + silu; z->silu(z) ----------------
__global__ void __launch_bounds__(256)
k_conv(const float* __restrict__ xz, const float* __restrict__ cw,
       const float* __restrict__ cb, float* __restrict__ xc,
       float* __restrict__ zsil){
  int idx = blockIdx.x*256 + threadIdx.x;
  int d = idx & 255;
  int l = (idx >> 8) & 4095;
  int b = idx >> 20;
  float v = cb[d];
  #pragma unroll
  for (int k = 0; k < 4; k++){
    int ls = l - 3 + k;
    if (ls >= 0) v += xz[(size_t)(b*4096 + ls)*512 + d] * cw[d*4 + k];
  }
  xc[idx] = siluf(v);
  float z = xz[(size_t)(b*4096 + l)*512 + 256 + d];
  zsil[idx] = siluf(z);
}

// ---------------- x-proj (dt,B,C) + delta ----------------
__global__ void __launch_bounds__(256)
k_proj(const float* __restrict__ xc, const float* __restrict__ xpT,
       const float* __restrict__ dtw, const float* __restrict__ dtb,
       float* __restrict__ delta, float* __restrict__ Bm, float* __restrict__ Cm){
  __shared__ float xt[32][260];
  __shared__ float pr[32][40];
  int tid = threadIdx.x;
  int m0 = blockIdx.x * 32;
  for (int i = tid; i < 32*256; i += 256){
    int t = i >> 8, d = i & 255;
    xt[t][d] = xc[(size_t)(m0+t)*256 + d];
  }
  __syncthreads();
  {
    int t = tid >> 3, j0 = tid & 7;
    float a0=0.f,a1=0.f,a2=0.f,a3=0.f,a4=0.f;
    for (int d = 0; d < 256; d++){
      float xv = xt[t][d];
      const float* wp = &xpT[d*40 + j0];
      a0 += xv*wp[0]; a1 += xv*wp[8]; a2 += xv*wp[16]; a3 += xv*wp[24]; a4 += xv*wp[32];
    }
    pr[t][j0] = a0; pr[t][j0+8] = a1; pr[t][j0+16] = a2; pr[t][j0+24] = a3; pr[t][j0+32] = a4;
  }
  __syncthreads();
  {
    int d = tid;
    float w[8];
    #pragma unroll
    for (int r = 0; r < 8; r++) w[r] = dtw[d*8+r];
    float bd = dtb[d];
    for (int t = 0; t < 32; t++){
      float val = bd;
      #pragma unroll
      for (int r = 0; r < 8; r++) val += pr[t][r]*w[r];
      delta[(size_t)(m0+t)*256 + d] = softplusf(val);
    }
  }
  for (int i = tid; i < 512; i += 256){
    int t = i >> 4, n = i & 15;
    Bm[(size_t)(m0+t)*16 + n] = pr[t][8+n];
    Cm[(size_t)(m0+t)*16 + n] = pr[t][24+n];
  }
}

// ---------------- chunked scan phase 1 ----------------
__global__ void __launch_bounds__(256)
k_scan1(const float* __restrict__ delta, const float* __restrict__ xc,
        const float* __restrict__ Bm, const float* __restrict__ Alog,
        float* __restrict__ P, float* __restrict__ Q){
  __shared__ float sd[64][16], sx[64][16], sb[64][16];
  int blk = blockIdx.x;
  int b = blk >> 10;
  int chunk = (blk >> 4) & 63;
  int dblk = blk & 15;
  int tid = threadIdx.x;
  size_t rowbase = (size_t)(b*4096 + chunk*64);
  for (int i = tid; i < 64*16; i += 256){
    int ii = i >> 4, dd = i & 15;
    sd[ii][dd] = delta[(rowbase + ii)*256 + dblk*16 + dd];
    sx[ii][dd] = xc  [(rowbase + ii)*256 + dblk*16 + dd];
    sb[ii][dd] = Bm  [(rowbase + ii)*16 + dd];
  }
  int dl = tid >> 4, n = tid & 15;
  int d = dblk*16 + dl;
  float An = -__expf(Alog[d*16 + n]);
  __syncthreads();
  float Pv = 1.f, Qv = 0.f;
  for (int i = 0; i < 64; i++){
    float dv = sd[i][dl];
    float a = __expf(dv * An);
    Qv = a*Qv + dv * sb[i][n] * sx[i][dl];
    Pv *= a;
  }
  size_t o = (size_t)(b*64+chunk)*4096 + dblk*256 + tid;
  P[o] = Pv; Q[o] = Qv;
}

// ---------------- chunked scan phase 2 ----------------
__global__ void __launch_bounds__(256)
k_scan2(const float* __restrict__ P, const float* __restrict__ Q,
        float* __restrict__ hs){
  int gid = blockIdx.x*256 + threadIdx.x;
  int b = gid >> 12, dn = gid & 4095;
  float h = 0.f;
  for (int ch = 0; ch < 64; ch++){
    size_t idx = (size_t)(b*64 + ch)*4096 + dn;
    hs[idx] = h;
    h = P[idx]*h + Q[idx];
  }
}

// ---------------- chunked scan phase 3 ----------------
__global__ void __launch_bounds__(256)
k_scan3(const float* __restrict__ delta, const float* __restrict__ xc,
        const float* __restrict__ Bm, const float* __restrict__ Cm,
        const float* __restrict__ zsil, const float* __restrict__ Alog,
        const float* __restrict__ Dv, const float* __restrict__ hs,
        float* __restrict__ y){
  __shared__ float sd[64][16], sx[64][16], sb[64][16], sc[64][16], sz[64][16], yt[64][16];
  int blk = blockIdx.x;
  int b = blk >> 10;
  int chunk = (blk >> 4) & 63;
  int dblk = blk & 15;
  int tid = threadIdx.x;
  size_t rowbase = (size_t)(b*4096 + chunk*64);
  for (int i = tid; i < 64*16; i += 256){
    int ii = i >> 4, dd = i & 15;
    sd[ii][dd] = delta[(rowbase + ii)*256 + dblk*16 + dd];
    sx[ii][dd] = xc  [(rowbase + ii)*256 + dblk*16 + dd];
    sz[ii][dd] = zsil[(rowbase + ii)*256 + dblk*16 + dd];
    sb[ii][dd] = Bm  [(rowbase + ii)*16 + dd];
    sc[ii][dd] = Cm  [(rowbase + ii)*16 + dd];
  }
  int dl = tid >> 4, n = tid & 15;
  int d = dblk*16 + dl;
  float An = -__expf(Alog[d*16 + n]);
  float h = hs[(size_t)(b*64+chunk)*4096 + dblk*256 + tid];
  float Dd = Dv[d];
  __syncthreads();
  for (int i = 0; i < 64; i++){
    float dv = sd[i][dl], xv = sx[i][dl];
    float a = __expf(dv * An);
    h = a*h + dv * sb[i][n] * xv;
    float ctr = h * sc[i][n];
    ctr += __shfl_xor(ctr, 1);
    ctr += __shfl_xor(ctr, 2);
    ctr += __shfl_xor(ctr, 4);
    ctr += __shfl_xor(ctr, 8);
    if (n == 0) yt[i][dl] = (ctr + Dd*xv) * sz[i][dl];
  }
  __syncthreads();
  for (int i = tid; i < 1024; i += 256){
    int ii = i >> 4, dd = i & 15;
    y[(rowbase + ii)*256 + dblk*16 + dd] = yt[ii][dd];
  }
}

// ---------------- spa out-proj: tiled GEMM 32x64 + GN partial stats ----------
// grid (256, 2); K=256. A = y [tok][256].
__global__ void __launch_bounds__(256)
k_outproj(const float* __restrict__ y, const float* __restrict__ outT,
          float* __restrict__ yproj, float* __restrict__ part){
  __shared__ float As[16][36];
  __shared__ float Bs[16][64];
  __shared__ float red1[2][4], red2[2][4];
  int tid = threadIdx.x;
  int bx = blockIdx.x, by = blockIdx.y;
  int m0 = bx*32, n0 = by*64;
  int b = m0 >> 12;
  int tx = tid & 15, ty = tid >> 4;
  float acc[2][4];
  #pragma unroll
  for (int i = 0; i < 2; i++)
    #pragma unroll
    for (int j = 0; j < 4; j++) acc[i][j] = 0.f;
  for (int k0 = 0; k0 < 256; k0 += 16){
    if (tid < 128){
      int m = tid >> 2, kk = (tid & 3)*4;
      float4 a = *(const float4*)(y + (size_t)(m0+m)*256 + k0+kk);
      As[kk+0][m] = a.x; As[kk+1][m] = a.y; As[kk+2][m] = a.z; As[kk+3][m] = a.w;
    }
    {
      int k = tid >> 4, n = (tid & 15)*4;
      *(float4*)&Bs[k][n] = *(const float4*)(outT + (size_t)(k0+k)*128 + n0+n);
    }
    __syncthreads();
    #pragma unroll
    for (int k = 0; k < 16; k++){
      float2 av = *(const float2*)&As[k][ty*2];
      float4 bv = *(const float4*)&Bs[k][tx*4];
      acc[0][0] += av.x*bv.x; acc[0][1] += av.x*bv.y; acc[0][2] += av.x*bv.z; acc[0][3] += av.x*bv.w;
      acc[1][0] += av.y*bv.x; acc[1][1] += av.y*bv.y; acc[1][2] += av.y*bv.z; acc[1][3] += av.y*bv.w;
    }
    __syncthreads();
  }
  float s1 = 0.f, s2 = 0.f;
  #pragma unroll
  for (int i = 0; i < 2; i++){
    float4 st; st.x = acc[i][0]; st.y = acc[i][1]; st.z = acc[i][2]; st.w = acc[i][3];
    s1 += st.x+st.y+st.z+st.w;
    s2 += st.x*st.x + st.y*st.y + st.z*st.z + st.w*st.w;
    *(float4*)(yproj + (size_t)(m0 + ty*2 + i)*128 + n0 + tx*4) = st;
  }
  s1 += __shfl_xor(s1,1);  s2 += __shfl_xor(s2,1);
  s1 += __shfl_xor(s1,2);  s2 += __shfl_xor(s2,2);
  s1 += __shfl_xor(s1,4);  s2 += __shfl_xor(s2,4);
  s1 += __shfl_xor(s1,16); s2 += __shfl_xor(s2,16);
  s1 += __shfl_xor(s1,32); s2 += __shfl_xor(s2,32);
  int lane = tid & 63, w = tid >> 6;
  if ((lane & 55) == 0){
    int gl = (lane >> 3) & 1;
    red1[gl][w] = s1; red2[gl][w] = s2;
  }
  __syncthreads();
  if (tid < 8){
    int gg = tid >> 1, which = tid & 1;
    int gl = gg - by*2;
    float v = 0.f;
    if (gl == 0 || gl == 1){
      v = which ? (red2[gl][0]+red2[gl][1]+red2[gl][2]+red2[gl][3])
                : (red1[gl][0]+red1[gl][1]+red1[gl][2]+red1[gl][3]);
    }
    int pblk = b*256 + (bx & 127) + by*128;
    part[(size_t)pblk*8 + tid] = v;
  }
}

// ---------------- spe A: in-proj + conv + silu (reg weights, lane=d) ----------
__global__ void __launch_bounds__(256)
k_spe_a(const float* __restrict__ h1, const float* __restrict__ in_w,
        const float* __restrict__ conv_w, const float* __restrict__ conv_b,
        float* __restrict__ xc2, float* __restrict__ xc2T,
        float* __restrict__ zsil2){
  __shared__ float s_in[4][128];
  int tid = threadIdx.x;
  int w = tid >> 6, lane = tid & 63;
  float wx[32], wz[32];
  {
    const float4* rx = (const float4*)(in_w + (size_t)lane*32);
    const float4* rz = (const float4*)(in_w + (size_t)(64+lane)*32);
    #pragma unroll
    for (int k = 0; k < 8; k++){
      float4 a = rx[k]; wx[k*4]=a.x; wx[k*4+1]=a.y; wx[k*4+2]=a.z; wx[k*4+3]=a.w;
      float4 b = rz[k]; wz[k*4]=b.x; wz[k*4+1]=b.y; wz[k*4+2]=b.z; wz[k*4+3]=b.w;
    }
  }
  float4 cwv = ((const float4*)conv_w)[lane];
  float cbv = conv_b[lane];
  for (int i = 0; i < 4; i++){
    int pix = blockIdx.x*16 + w*4 + i;
    float2 hv = ((const float2*)(h1 + (size_t)pix*128))[lane];
    s_in[w][2*lane] = hv.x; s_in[w][2*lane+1] = hv.y;
    float xpr[4], zs[4];
    #pragma unroll
    for (int l = 0; l < 4; l++){
      const float4* sv = (const float4*)&s_in[w][l*32];
      float ax = 0.f, az = 0.f;
      #pragma unroll
      for (int c4 = 0; c4 < 8; c4++){
        float4 v = sv[c4];
        ax += v.x*wx[c4*4] + v.y*wx[c4*4+1] + v.z*wx[c4*4+2] + v.w*wx[c4*4+3];
        az += v.x*wz[c4*4] + v.y*wz[c4*4+1] + v.z*wz[c4*4+2] + v.w*wz[c4*4+3];
      }
      xpr[l] = ax; zs[l] = siluf(az);
    }
    #pragma unroll
    for (int l = 0; l < 4; l++){
      float v = cbv;
      if (l >= 3) v += xpr[l-3]*cwv.x;
      if (l >= 2) v += xpr[l-2]*cwv.y;
      if (l >= 1) v += xpr[l-1]*cwv.z;
      v += xpr[l]*cwv.w;
      float sx = siluf(v);
      int tok = pix*4 + l;
      xc2 [(size_t)tok*64 + lane] = sx;
      xc2T[(size_t)lane*32768 + tok] = sx;
      zsil2[(size_t)tok*64 + lane] = zs[l];
    }
  }
}

// ---------------- spe B: x-proj GEMM, thread = token --------------------------
__global__ void __launch_bounds__(256)
k_spe_b(const float* __restrict__ xc2T, const float* __restrict__ xpw,
        float* __restrict__ proj){
  int tok = blockIdx.x*256 + threadIdx.x;
  float xcv[64];
  #pragma unroll 64
  for (int dd = 0; dd < 64; dd++) xcv[dd] = xc2T[(size_t)dd*32768 + tok];
  float* pr = proj + (size_t)tok*36;
  #pragma unroll 2
  for (int j = 0; j < 34; j++){
    const float4* wr = (const float4*)(xpw + j*64);
    float a = 0.f;
    #pragma unroll
    for (int k = 0; k < 16; k++){
      float4 wv = wr[k];
      a += xcv[k*4]*wv.x + xcv[k*4+1]*wv.y + xcv[k*4+2]*wv.z + xcv[k*4+3]*wv.w;
    }
    pr[j] = a;
  }
}

// ---------------- spe C: delta + scan + gate (lane=d, 4 pixels/wave) ----------
__global__ void __launch_bounds__(256)
k_spe_c(const float* __restrict__ xc2, const float* __restrict__ zsil2,
        const float* __restrict__ proj, const float* __restrict__ dt_w,
        const float* __restrict__ dt_b, const float* __restrict__ Alog,
        const float* __restrict__ Dvec, float* __restrict__ yg){
  int tid = threadIdx.x;
  int w = tid >> 6, lane = tid & 63;
  float2 dtwv = ((const float2*)dt_w)[lane];
  float dbv = dt_b[lane], Dd = Dvec[lane];
  float An[16];
  {
    const float4* ar = (const float4*)(Alog + (size_t)lane*16);
    #pragma unroll
    for (int k = 0; k < 4; k++){
      float4 a = ar[k];
      An[k*4]   = -__expf(a.x); An[k*4+1] = -__expf(a.y);
      An[k*4+2] = -__expf(a.z); An[k*4+3] = -__expf(a.w);
    }
  }
  for (int i = 0; i < 4; i++){
    int pix = blockIdx.x*16 + w*4 + i;
    float h[16];
    #pragma unroll
    for (int n = 0; n < 16; n++) h[n] = 0.f;
    #pragma unroll
    for (int l = 0; l < 4; l++){
      int tok = pix*4 + l;
      float pj[36];
      {
        const float4* pr = (const float4*)(proj + (size_t)tok*36);
        #pragma unroll
        for (int k = 0; k < 9; k++){
          float4 v = pr[k];
          pj[k*4]=v.x; pj[k*4+1]=v.y; pj[k*4+2]=v.z; pj[k*4+3]=v.w;
        }
      }
      float xv = xc2[(size_t)tok*64 + lane];
      float zv = zsil2[(size_t)tok*64 + lane];
      float dt = softplusf(dbv + pj[0]*dtwv.x + pj[1]*dtwv.y);
      float ys = 0.f;
      #pragma unroll
      for (int n = 0; n < 16; n++){
        float a = __expf(dt * An[n]);
        h[n] = a*h[n] + dt * pj[2+n] * xv;
        ys += h[n] * pj[18+n];
      }
      yg[(size_t)tok*64 + lane] = (ys + Dd*xv) * zv;
    }
  }
}

// ---------------- spe D: out-proj GEMM + GN partial stats ---------------------
__global__ void __launch_bounds__(256)
k_spe_d(const float* __restrict__ yg, const float* __restrict__ out_w,
        float* __restrict__ y2, float* __restrict__ part){
  __shared__ float ldsWT[64*32];
  __shared__ float bst[8];
  int tid = threadIdx.x;
  for (int i = tid; i < 2048; i += 256){
    int c2 = i >> 6, dd = i & 63;
    ldsWT[dd*32 + c2] = out_w[i];
  }
  if (tid < 8) bst[tid] = 0.f;
  __syncthreads();
  int w = tid >> 6, lane = tid & 63;
  int c2 = lane & 31, slot = lane >> 5;
  int tokbase = blockIdx.x*64 + w*16 + slot;
  float acc[8];
  #pragma unroll
  for (int i = 0; i < 8; i++) acc[i] = 0.f;
  for (int dd4 = 0; dd4 < 16; dd4++){
    float w0 = ldsWT[(dd4*4+0)*32 + c2];
    float w1 = ldsWT[(dd4*4+1)*32 + c2];
    float w2 = ldsWT[(dd4*4+2)*32 + c2];
    float w3 = ldsWT[(dd4*4+3)*32 + c2];
    #pragma unroll
    for (int i = 0; i < 8; i++){
      int tok = tokbase + 2*i;
      float4 yv = ((const float4*)(yg + (size_t)tok*64))[dd4];
      acc[i] += yv.x*w0 + yv.y*w1 + yv.z*w2 + yv.w*w3;
    }
  }
  #pragma unroll
  for (int i = 0; i < 8; i++){
    int tok = tokbase + 2*i;
    int pix = tok >> 2, l = tok & 3;
    y2[(size_t)pix*128 + l*32 + c2] = acc[i];
    float s1 = acc[i], s2 = acc[i]*acc[i];
    s1 += __shfl_xor(s1,1);  s2 += __shfl_xor(s2,1);
    s1 += __shfl_xor(s1,2);  s2 += __shfl_xor(s2,2);
    s1 += __shfl_xor(s1,4);  s2 += __shfl_xor(s2,4);
    s1 += __shfl_xor(s1,8);  s2 += __shfl_xor(s2,8);
    s1 += __shfl_xor(s1,16); s2 += __shfl_xor(s2,16);
    if (c2 == 0){
      atomicAdd(&bst[l*2+0], s1);
      atomicAdd(&bst[l*2+1], s2);
    }
  }
  __syncthreads();
  if (tid < 8) part[(size_t)blockIdx.x*8 + tid] = bst[tid];
}

// ---------------- fuse: GN(spa)+GN(spe)+h1 -> feat, logits ----------------
__global__ void __launch_bounds__(256)
k_fuse(const float* __restrict__ h1, const float* __restrict__ yproj,
       const float* __restrict__ y2, const float* __restrict__ stats,
       const float* __restrict__ spa_g, const float* __restrict__ spa_b,
       const float* __restrict__ spe_g, const float* __restrict__ spe_b,
       const float* __restrict__ fuse_w, const float* __restrict__ cls_w,
       const float* __restrict__ cls_b, float* __restrict__ feat,
       float* __restrict__ logits){
  __shared__ float ft[2][128];
  int tid = threadIdx.x;
  int pixl = tid >> 7, c = tid & 127;
  int pix = blockIdx.x*2 + pixl;
  int b = pix >> 12, g = c >> 5;
  float m1 = stats[16 + (b*4+g)*2]   * (1.f/NG);
  float v1 = stats[16 + (b*4+g)*2+1] * (1.f/NG) - m1*m1;
  float m2 = stats[32 + (b*4+g)*2]   * (1.f/NG);
  float v2 = stats[32 + (b*4+g)*2+1] * (1.f/NG) - m2*m2;
  float h = h1[(size_t)pix*128 + c];
  float sa = siluf((yproj[(size_t)pix*128+c] - m1)*rsqrtf(v1+1e-5f)*spa_g[c] + spa_b[c]) + h;
  float sp = h + siluf((y2[(size_t)pix*128+c] - m2)*rsqrtf(v2+1e-5f)*spe_g[c] + spe_b[c]);
  float e0 = __expf(fuse_w[0]), e1 = __expf(fuse_w[1]);
  float w0 = e0/(e0+e1), w1 = e1/(e0+e1);
  float f = sa*w0 + sp*w1 + h;
  feat[(size_t)pix*128+c] = f;
  ft[pixl][c] = f;
  __syncthreads();
  if (tid < 20){
    int pl = (tid >= 10) ? 1 : 0;
    int o = tid - pl*10;
    float acc = cls_b[o];
    for (int cc = 0; cc < 128; cc++) acc += ft[pl][cc]*cls_w[o*128+cc];
    logits[(size_t)(blockIdx.x*2 + pl)*16 + o] = acc;
  }
}

// ---------------- depthwise 3x3 on feat + GN partial stats ----------------
__global__ void __launch_bounds__(256)
k_dw(const float* __restrict__ feat, const float* __restrict__ dww,
     float* __restrict__ epre, float* __restrict__ part){
  __shared__ float red1[4][64], red2[4][64];
  int tid = threadIdx.x;
  int pixl = tid >> 7, c = tid & 127;
  int pix = blockIdx.x*2 + pixl;
  int b = pix >> 12, p = pix & 4095, yy = p >> 6, xx = p & 63;
  float acc = 0.f;
  for (int dy = -1; dy <= 1; dy++){
    int ny = yy + dy; if (ny < 0 || ny > 63) continue;
    for (int dx = -1; dx <= 1; dx++){
      int nx = xx + dx; if (nx < 0 || nx > 63) continue;
      acc += feat[(size_t)((b<<12)|(ny<<6)|nx)*128 + c] * dww[c*9 + (dy+1)*3 + (dx+1)];
    }
  }
  epre[(size_t)pix*128 + c] = acc;
  int g = c >> 5;
  int idx = (c & 31) | (pixl << 5);
  red1[g][idx] = acc; red2[g][idx] = acc*acc;
  __syncthreads();
  int rg = tid >> 6, ridx = tid & 63;
  for (int s = 32; s >= 1; s >>= 1){
    if (ridx < s){ red1[rg][ridx] += red1[rg][ridx+s]; red2[rg][ridx] += red2[rg][ridx+s]; }
    __syncthreads();
  }
  if (ridx == 0){
    part[(size_t)blockIdx.x*8 + rg*2+0] = red1[rg][0];
    part[(size_t)blockIdx.x*8 + rg*2+1] = red2[rg][0];
  }
}

// ---------------- edge + local avg + final output ----------------
__global__ void __launch_bounds__(256)
k_final(const float* __restrict__ epre, const float* __restrict__ logits,
        const float* __restrict__ stats, const float* __restrict__ rg_g,
        const float* __restrict__ rg_b, const float* __restrict__ pw_w,
        const float* __restrict__ pw_b, const float* __restrict__ alpha,
        float* __restrict__ outp){
  __shared__ float part[4];
  __shared__ float edge_s[2];
  int tid = threadIdx.x;
  int pixl = tid >> 7, c = tid & 127;
  int pix = blockIdx.x*2 + pixl;
  int b = pix >> 12, p = pix & 4095, yy = p >> 6, xx = p & 63;
  int g = c >> 5;
  float m = stats[48 + (b*4+g)*2]   * (1.f/NG);
  float v = stats[48 + (b*4+g)*2+1] * (1.f/NG) - m*m;
  float e = epre[(size_t)pix*128+c];
  float en = siluf((e-m)*rsqrtf(v+1e-5f)*rg_g[c] + rg_b[c]);
  float pv = en * pw_w[c];
  pv += __shfl_xor(pv,1);  pv += __shfl_xor(pv,2);  pv += __shfl_xor(pv,4);
  pv += __shfl_xor(pv,8);  pv += __shfl_xor(pv,16); pv += __shfl_xor(pv,32);
  if ((tid & 63) == 0) part[tid>>6] = pv;
  __syncthreads();
  if (tid < 2) edge_s[tid] = sigm(part[tid*2] + part[tid*2+1] + pw_b[0]);
  __syncthreads();
  if (c < 10){
    float ed = edge_s[pixl];
    int o = c;
    float lg = logits[(size_t)pix*16 + o];
    float loc = 0.f;
    for (int dy = -1; dy <= 1; dy++){
      int ny = yy+dy; if (ny < 0 || ny > 63) continue;
      for (int dx = -1; dx <= 1; dx++){
        int nx = xx+dx; if (nx < 0 || nx > 63) continue;
        loc += logits[(size_t)((b<<12)|(ny<<6)|nx)*16 + o];
      }
    }
    loc *= (1.f/9.f);
    outp[(size_t)((b*10+o)<<12) + p] = lg + alpha[0]*(1.f-ed)*(loc - lg);
  }
}

extern "C" void kernel_launch(void* const* d_in, const int* in_sizes, int n_in,
                              void* d_out, int out_size, void* d_ws, size_t ws_size,
                              hipStream_t stream){
  const float* x          = (const float*)d_in[0];
  const float* pe_w       = (const float*)d_in[1];
  const float* pe_b       = (const float*)d_in[2];
  const float* pe_gn_g    = (const float*)d_in[3];
  const float* pe_gn_b    = (const float*)d_in[4];
  const float* spa_in_w   = (const float*)d_in[5];
  const float* spa_conv_w = (const float*)d_in[6];
  const float* spa_conv_b = (const float*)d_in[7];
  const float* spa_xproj_w= (const float*)d_in[8];
  const float* spa_dt_w   = (const float*)d_in[9];
  const float* spa_dt_b   = (const float*)d_in[10];
  const float* spa_Alog   = (const float*)d_in[11];
  const float* spa_D      = (const float*)d_in[12];
  const float* spa_out_w  = (const float*)d_in[13];
  const float* spa_gn_g   = (const float*)d_in[14];
  const float* spa_gn_b   = (const float*)d_in[15];
  const float* spe_in_w   = (const float*)d_in[16];
  const float* spe_conv_w = (const float*)d_in[17];
  const float* spe_conv_b = (const float*)d_in[18];
  const float* spe_xproj_w= (const float*)d_in[19];
  const float* spe_dt_w   = (const float*)d_in[20];
  const float* spe_dt_b   = (const float*)d_in[21];
  const float* spe_Alog   = (const float*)d_in[22];
  const float* spe_D      = (const float*)d_in[23];
  const float* spe_out_w  = (const float*)d_in[24];
  const float* spe_gn_g   = (const float*)d_in[25];
  const float* spe_gn_b   = (const float*)d_in[26];
  const float* fuse_w     = (const float*)d_in[27];
  const float* cls_w      = (const float*)d_in[28];
  const float* cls_b      = (const float*)d_in[29];
  const float* ref_dw_w   = (const float*)d_in[30];
  const float* ref_gn_g   = (const float*)d_in[31];
  const float* ref_gn_b   = (const float*)d_in[32];
  const float* ref_pw_w   = (const float*)d_in[33];
  const float* ref_pw_b   = (const float*)d_in[34];
  const float* alpha      = (const float*)d_in[35];
  float* ws  = (float*)d_ws;
  float* out = (float*)d_out;

  float* partPE  = ws + WS_Y;
  float* partSPA = ws + WS_HS;
  float* partSPE = ws + WS_Q;
  float* partDW  = ws + WS_P;
  float* xc2   = ws + WS_XC;
  float* xc2T  = ws + WS_ZSIL;
  float* zsil2 = ws + WS_DELTA;
  float* proj  = ws + WS_BM;
  float* yg    = ws + WS_Y;

  k_transpose<<<64,256,0,stream>>>(pe_w, spa_in_w, spa_out_w, spa_xproj_w,
      ws+WS_PEWT, ws+WS_INWT, ws+WS_OUTWT, ws+WS_XPWT);
  k_pe<<<dim3(256,2),256,0,stream>>>(x, ws+WS_PEWT, pe_b, ws+WS_H1PRE, partPE);
  k_red<<<16,256,0,stream>>>(partPE, ws+WS_STATS+0, 256);
  k_gnsilu<<<4096,256,0,stream>>>(ws+WS_H1PRE, ws+WS_STATS, pe_gn_g, pe_gn_b, ws+WS_H1);
  k_xz<<<dim3(128,8),256,0,stream>>>(ws+WS_H1, ws+WS_INWT, ws+WS_XZ);
  k_conv<<<8192,256,0,stream>>>(ws+WS_XZ, spa_conv_w, spa_conv_b, ws+WS_XC, ws+WS_ZSIL);
  k_proj<<<256,256,0,stream>>>(ws+WS_XC, ws+WS_XPWT, spa_dt_w, spa_dt_b,
      ws+WS_DELTA, ws+WS_BM, ws+WS_CM);
  k_scan1<<<2048,256,0,stream>>>(ws+WS_DELTA, ws+WS_XC, ws+WS_BM, spa_Alog, ws+WS_P, ws+WS_Q);
  k_scan2<<<32,256,0,stream>>>(ws+WS_P, ws+WS_Q, ws+WS_HS);
  k_scan3<<<2048,256,0,stream>>>(ws+WS_DELTA, ws+WS_XC, ws+WS_BM, ws+WS_CM,
      ws+WS_ZSIL, spa_Alog, spa_D, ws+WS_HS, ws+WS_Y);
  k_outproj<<<dim3(256,2),256,0,stream>>>(ws+WS_Y, ws+WS_OUTWT, ws+WS_H1PRE, partSPA);
  k_red<<<16,256,0,stream>>>(partSPA, ws+WS_STATS+16, 256);
  k_spe_a<<<512,256,0,stream>>>(ws+WS_H1, spe_in_w, spe_conv_w, spe_conv_b,
      xc2, xc2T, zsil2);
  k_spe_b<<<128,256,0,stream>>>(xc2T, spe_xproj_w, proj);
  k_spe_c<<<512,256,0,stream>>>(xc2, zsil2, proj, spe_dt_w, spe_dt_b,
      spe_Alog, spe_D, yg);
  k_spe_d<<<512,256,0,stream>>>(yg, spe_out_w, ws+WS_Y2, partSPE);
  k_red<<<16,256,0,stream>>>(partSPE, ws+WS_STATS+32, 256);
  k_fuse<<<4096,256,0,stream>>>(ws+WS_H1, ws+WS_H1PRE, ws+WS_Y2, ws+WS_STATS,
      spa_gn_g, spa_gn_b, spe_gn_g, spe_gn_b, fuse_w, cls_w, cls_b,
      ws+WS_FEAT, ws+WS_LOG);
  k_dw<<<4096,256,0,stream>>>(ws+WS_FEAT, ref_dw_w, ws+WS_Y, partDW);
  k_red<<<16,256,0,stream>>>(partDW, ws+WS_STATS+48, 2048);
  k_final<<<4096,256,0,stream>>>(ws+WS_Y, ws+WS_LOG, ws+WS_STATS,
      ref_gn_g, ref_gn_b, ref_pw_w, ref_pw_b, alpha, out);
  (void)in_sizes; (void)n_in; (void)out_size; (void)ws_size;
}